// Round 5
// baseline (409.201 us; speedup 1.0000x reference)
//
#include <hip/hip_runtime.h>
#include <hip/hip_bf16.h>
#include <math.h>

#define DEV static __device__ __forceinline__

typedef __hip_bfloat16 bf16;
typedef __attribute__((ext_vector_type(8))) short bf16x8;   // 8 bf16 = 4 VGPRs
typedef __attribute__((ext_vector_type(4))) short bf16x4;   // 4 bf16 = 2 VGPRs
typedef __attribute__((ext_vector_type(4))) float f32x4;

static constexpr int D_MODEL = 1024;
static constexpr int D_INNER = 2048;
static constexpr int D_STATE = 16;
static constexpr int DT_RANK = 64;
static constexpr int B_SZ   = 2;
static constexpr int L_SEQ  = 2048;
static constexpr int T_TOK  = B_SZ * L_SEQ;   // 4096 tokens
static constexpr int LC     = 64;             // scan chunk length
static constexpr int NC     = L_SEQ / LC;     // 32 chunks per sequence
static constexpr int NXP    = DT_RANK + 2 * D_STATE;   // 96
static constexpr int KSPLIT = 8;              // x_proj split-K factor

// params (f32) layout inside ws
static constexpr int P_CONVW = 0;        // [2048*4]
static constexpr int P_CONVB = 8192;     // [2048]
static constexpr int P_DTB   = 10240;    // [2048]
static constexpr int P_ALOG  = 12288;    // [2048*16]
static constexpr int P_DW    = 45056;    // [2048]
static constexpr int P_LNW   = 47104;    // [1024]
static constexpr int P_LNB   = 48128;    // [1024]
static constexpr int P_TOT   = 49152;

DEV float bf2f(bf16 x) { return __bfloat162float(x); }
DEV bf16  f2bf(float x) { return __float2bfloat16(x); }
DEV float sigmoidf_(float x) { return 1.0f / (1.0f + __expf(-x)); }
DEV float s2f(short s) { bf16 b; __builtin_memcpy(&b, &s, 2); return bf2f(b); }
DEV short f2s(float x) { bf16 b = f2bf(x); short s; __builtin_memcpy(&s, &b, 2); return s; }

DEV bool probe_f32(const unsigned short* probe) { return probe[1] == 0; }

DEV void async_copy16(const void* g, void* l) {
  // DMA 16 B/lane: LDS dest = wave-uniform base + lane*16 (m97-verified)
  __builtin_amdgcn_global_load_lds(
      (const __attribute__((address_space(1))) void*)g,
      (__attribute__((address_space(3))) void*)l, 16, 0, 0);
}

template <int N>
DEV void vm_wait() {
  if constexpr (N == 8)      asm volatile("s_waitcnt vmcnt(8)" ::: "memory");
  else if constexpr (N == 6) asm volatile("s_waitcnt vmcnt(6)" ::: "memory");
  else                       asm volatile("s_waitcnt vmcnt(0)" ::: "memory");
}

// ---------------------------------------------------------------------------
// fused input normalization: ALL 12 tensors in one launch (8 elems/thread,
// vectorized stores).
// ---------------------------------------------------------------------------
__global__ void cvt_all(const void* s0, const void* s1, const void* s2,
                        const void* s3, const void* s4,
                        const void* s5, const void* s6, const void* s7,
                        const void* s8, const void* s9, const void* s10,
                        const void* s11,
                        bf16* d0, bf16* d1, bf16* d2, bf16* d3, bf16* d4,
                        float* params,
                        const unsigned short* __restrict__ probe)
{
  long i = (long)(blockIdx.x * 256 + threadIdx.x) * 8;
  const void* src; long off;
  bf16* dstb = nullptr; float* dstf = nullptr;
  if      (i <  4194304) { src = s0;  dstb = d0; off = i; }
  else if (i <  8388608) { src = s1;  dstb = d1; off = i - 4194304; }
  else if (i <  8585216) { src = s2;  dstb = d2; off = i - 8388608; }
  else if (i <  8716288) { src = s3;  dstb = d3; off = i - 8585216; }
  else if (i < 10813440) { src = s4;  dstb = d4; off = i - 8716288; }
  else if (i < 10821632) { src = s5;  dstf = params + P_CONVW; off = i - 10813440; }
  else if (i < 10823680) { src = s6;  dstf = params + P_CONVB; off = i - 10821632; }
  else if (i < 10825728) { src = s7;  dstf = params + P_DTB;   off = i - 10823680; }
  else if (i < 10858496) { src = s8;  dstf = params + P_ALOG;  off = i - 10825728; }
  else if (i < 10860544) { src = s9;  dstf = params + P_DW;    off = i - 10858496; }
  else if (i < 10861568) { src = s10; dstf = params + P_LNW;   off = i - 10860544; }
  else if (i < 10862592) { src = s11; dstf = params + P_LNB;   off = i - 10861568; }
  else return;
  bool isf32 = probe_f32(probe);
  float v[8];
  if (isf32) {
    float4 a = *(const float4*)((const float*)src + off);
    float4 b = *(const float4*)((const float*)src + off + 4);
    v[0]=a.x; v[1]=a.y; v[2]=a.z; v[3]=a.w;
    v[4]=b.x; v[5]=b.y; v[6]=b.z; v[7]=b.w;
  } else {
    bf16x8 t = *(const bf16x8*)((const bf16*)src + off);
    #pragma unroll
    for (int k = 0; k < 8; ++k) { short sk = t[k]; v[k] = s2f(sk); }
  }
  if (dstb) {
    bf16x8 o;
    #pragma unroll
    for (int k = 0; k < 8; ++k) o[k] = f2s(v[k]);
    *(bf16x8*)(dstb + off) = o;
  } else {
    f32x4 a = {v[0], v[1], v[2], v[3]};
    f32x4 b = {v[4], v[5], v[6], v[7]};
    *(f32x4*)(dstf + off)     = a;
    *(f32x4*)(dstf + off + 4) = b;
  }
}

// ---------------------------------------------------------------------------
// 8-wave pipelined GEMM: BM=BN=256, BK=64, wave tile 128x64 (2M x 4N).
// LDS 2-slot ring (128 KiB), counted vmcnt(8) per tile, compiler-scheduled
// core, 128B LDS rows + 8-chunk XOR swizzle (0 bank conflicts).
// NEW: XCD-chunked blockIdx swizzle (T1, bijective: nwg%8==0) — each XCD
// gets a contiguous stripe so same-panel blocks share that XCD's L2.
// MODE 0: in_proj  -> o0=u_pre bf16, o1=silu(z) bf16
// MODE 3: out_proj split-K=4 -> bf16 partials z0,1->o0, z2,3->o1
// ---------------------------------------------------------------------------
DEV void stage256(const bf16* __restrict__ src, int ld, int base_row, int k0,
                  char* dst_base, int tid) {
  #pragma unroll
  for (int j = 0; j < 4; ++j) {
    int p   = j * 8192 + tid * 16;           // linear LDS dest byte
    int row = p >> 7;                        // 0..255 (128B rows)
    int ck  = ((p >> 4) & 7) ^ (row & 7);    // inverse-swizzled 16B chunk
    async_copy16(src + (size_t)(base_row + row) * ld + k0 + ck * 8,
                 dst_base + j * 8192 + (tid >> 6) * 1024);
  }
}

template <int MODE>
DEV void gemm_pipe256(const bf16* __restrict__ A, const bf16* __restrict__ B,
                      int M, int K, int ld,
                      void* __restrict__ o0, void* __restrict__ o1)
{
  __shared__ __align__(16) char ring[2 * 65536];   // 128 KiB

  // XCD-chunked bijective swizzle over the full linear grid
  unsigned lin = blockIdx.x + gridDim.x * (blockIdx.y + gridDim.y * blockIdx.z);
  unsigned nwg = gridDim.x * gridDim.y * gridDim.z;
  unsigned cpx = nwg >> 3;                 // nwg % 8 == 0 by construction
  unsigned nid = (lin & 7) * cpx + (lin >> 3);
  unsigned bx  = nid % gridDim.x;
  unsigned tq  = nid / gridDim.x;
  unsigned by  = tq % gridDim.y;
  unsigned bz  = tq / gridDim.y;

  if (MODE == 3) {
    A += (size_t)bz * K;
    B += (size_t)bz * K;
  }
  const int tid  = threadIdx.x;
  const int wave = tid >> 6;
  const int lane = tid & 63;
  const int bm = bx * 256;
  const int bn = by * 256;
  const int wmr = (wave >> 2) * 128;     // 0/128: A row group (128 rows)
  const int wnr = (wave & 3) * 64;       // 0..192: B row group (64 rows)
  const int fr = lane & 15;
  const int fq = lane >> 4;              // 0..3
  const int frs = lane & 7;
  const int NT = K / 64;

  f32x4 acc[8][4];
  #pragma unroll
  for (int i = 0; i < 8; ++i)
    #pragma unroll
    for (int j = 0; j < 4; ++j)
      #pragma unroll
      for (int r = 0; r < 4; ++r) acc[i][j][r] = 0.0f;

  // prologue: stage tiles 0 and 1 (16 loads/thread in flight)
  stage256(A, ld, bm, 0,  ring,                 tid);
  stage256(B, ld, bn, 0,  ring + 32768,         tid);
  stage256(A, ld, bm, 64, ring + 65536,         tid);
  stage256(B, ld, bn, 64, ring + 65536 + 32768, tid);

  #pragma unroll 1
  for (int tk = 0; tk < NT; ++tk) {
    // tile tk's 8 loads are oldest; tile tk+1's 8 may stay in flight
    if (tk < NT - 1) vm_wait<8>();
    else             vm_wait<0>();
    __builtin_amdgcn_s_barrier();

    const char* sa = ring + (size_t)(tk & 1) * 65536;

    // B fragments (8 ds_read_b128) — compiler schedules waits
    bf16x8 bg[4][2];
    #pragma unroll
    for (int ni = 0; ni < 4; ++ni)
      #pragma unroll
      for (int kk = 0; kk < 2; ++kk)
        bg[ni][kk] = *(const bf16x8*)(sa + 32768
                       + (size_t)(wnr + ni * 16 + fr) * 128
                       + (((kk * 4 + fq) ^ frs) * 16));

    __builtin_amdgcn_s_setprio(1);
    #pragma unroll
    for (int mh = 0; mh < 2; ++mh) {
      bf16x8 af[4][2];
      #pragma unroll
      for (int mi = 0; mi < 4; ++mi)
        #pragma unroll
        for (int kk = 0; kk < 2; ++kk)
          af[mi][kk] = *(const bf16x8*)(sa
                         + (size_t)(wmr + mh * 64 + mi * 16 + fr) * 128
                         + (((kk * 4 + fq) ^ frs) * 16));
      #pragma unroll
      for (int kk = 0; kk < 2; ++kk)
        #pragma unroll
        for (int mi = 0; mi < 4; ++mi)
          #pragma unroll
          for (int ni = 0; ni < 4; ++ni)
            acc[mh * 4 + mi][ni] = __builtin_amdgcn_mfma_f32_16x16x32_bf16(
                af[mi][kk], bg[ni][kk], acc[mh * 4 + mi][ni], 0, 0, 0);
    }
    __builtin_amdgcn_s_setprio(0);

    // all reads already consumed -> ~free, but makes the stage below
    // provably WAR-safe across the barrier.
    asm volatile("s_waitcnt lgkmcnt(0)" ::: "memory");
    __builtin_amdgcn_s_barrier();
    if (tk + 2 < NT) {
      char* sn = ring + (size_t)(tk & 1) * 65536;
      stage256(A, ld, bm, (tk + 2) * 64, sn,         tid);
      stage256(B, ld, bn, (tk + 2) * 64, sn + 32768, tid);
    }
  }

  const int er = (lane >> 4) * 4;     // C/D: row = er + reg, col = lane&15
  const int ec = lane & 15;
  #pragma unroll
  for (int ai = 0; ai < 8; ++ai) {
    #pragma unroll
    for (int ni = 0; ni < 4; ++ni) {
      #pragma unroll
      for (int r = 0; r < 4; ++r) {
        int row = bm + wmr + ai * 16 + er + r;   // token index
        int col = bn + wnr + ni * 16 + ec;
        float v = acc[ai][ni][r];
        if (MODE == 0) {
          if (col < D_INNER) ((bf16*)o0)[(size_t)row * D_INNER + col] = f2bf(v);
          else               ((bf16*)o1)[(size_t)row * D_INNER + (col - D_INNER)] = f2bf(v * sigmoidf_(v));
        } else {
          bf16* dst = (bz < 2) ? (bf16*)o0 : (bf16*)o1;
          dst[(((size_t)(bz & 1)) * M + row) * D_MODEL + col] = f2bf(v);
        }
      }
    }
  }
}

// ---------------------------------------------------------------------------
// BK=32 register-staged GEMM body (x_proj split-K -> f32 partials)
// ---------------------------------------------------------------------------
template <int MODE>
DEV void gemm_body32(const bf16* __restrict__ A, const bf16* __restrict__ B,
                     int M, int N, int K, int ld,
                     void* __restrict__ o0, const void* __restrict__ e0)
{
  __shared__ __align__(16) bf16 As[128 * 32];
  __shared__ __align__(16) bf16 Bs[128 * 32];
  if (MODE == 1) {
    A += (size_t)blockIdx.z * K;
    B += (size_t)blockIdx.z * K;
  }
  const int tid  = threadIdx.x;
  const int wave = tid >> 6;
  const int lane = tid & 63;
  const int bm = blockIdx.x * 128;
  const int bn = blockIdx.y * 128;
  const int wm = (wave >> 1) * 64;
  const int wn = (wave & 1) * 64;

  f32x4 acc[4][4];
  #pragma unroll
  for (int i = 0; i < 4; ++i)
    #pragma unroll
    for (int j = 0; j < 4; ++j)
      #pragma unroll
      for (int r = 0; r < 4; ++r) acc[i][j][r] = 0.0f;

  const int ar0 = tid >> 2;
  const int ar1 = ar0 + 64;
  const int ac  = (tid & 3) * 8;
  const int fr = lane & 15;
  const int fk = (lane >> 4) * 8;

  for (int k0 = 0; k0 < K; k0 += 32) {
    bf16x8 a0 = *(const bf16x8*)(A + (size_t)(bm + ar0) * ld + k0 + ac);
    bf16x8 a1 = *(const bf16x8*)(A + (size_t)(bm + ar1) * ld + k0 + ac);
    int r0 = bn + ar0; if (r0 > N - 1) r0 = N - 1;
    int r1 = bn + ar1; if (r1 > N - 1) r1 = N - 1;
    bf16x8 b0 = *(const bf16x8*)(B + (size_t)r0 * ld + k0 + ac);
    bf16x8 b1 = *(const bf16x8*)(B + (size_t)r1 * ld + k0 + ac);
    __syncthreads();
    *(bf16x8*)(As + ar0 * 32 + ac) = a0;
    *(bf16x8*)(As + ar1 * 32 + ac) = a1;
    *(bf16x8*)(Bs + ar0 * 32 + ac) = b0;
    *(bf16x8*)(Bs + ar1 * 32 + ac) = b1;
    __syncthreads();

    bf16x8 af[4], bg[4];
    #pragma unroll
    for (int mi = 0; mi < 4; ++mi)
      af[mi] = *(const bf16x8*)(As + (wm + mi * 16 + fr) * 32 + fk);
    #pragma unroll
    for (int ni = 0; ni < 4; ++ni)
      bg[ni] = *(const bf16x8*)(Bs + (wn + ni * 16 + fr) * 32 + fk);
    #pragma unroll
    for (int mi = 0; mi < 4; ++mi)
      #pragma unroll
      for (int ni = 0; ni < 4; ++ni)
        acc[mi][ni] = __builtin_amdgcn_mfma_f32_16x16x32_bf16(af[mi], bg[ni], acc[mi][ni], 0, 0, 0);
  }

  const int er = (lane >> 4) * 4;
  const int ec = lane & 15;
  #pragma unroll
  for (int mi = 0; mi < 4; ++mi) {
    #pragma unroll
    for (int ni = 0; ni < 4; ++ni) {
      #pragma unroll
      for (int r = 0; r < 4; ++r) {
        int row = bm + wm + mi * 16 + er + r;
        int col = bn + wn + ni * 16 + ec;
        if (col >= N) continue;
        float v = acc[mi][ni][r];
        ((float*)o0)[((size_t)blockIdx.z * M + row) * N + col] = v;
      }
    }
  }
}

// distinct names so rocprof disambiguates the stages
__global__ void __launch_bounds__(512, 2) k_inproj(const bf16* A, const bf16* B,
    void* o0, void* o1) {
  gemm_pipe256<0>(A, B, T_TOK, D_MODEL, D_MODEL, o0, o1);
}
__global__ void __launch_bounds__(512, 2) k_outproj(const bf16* A, const bf16* B,
    void* o0, void* o1) {
  gemm_pipe256<3>(A, B, T_TOK, D_INNER / 4, D_INNER, o0, o1);
}
__global__ void __launch_bounds__(256) k_xproj(const bf16* A, const bf16* B,
    void* o0) {
  gemm_body32<1>(A, B, T_TOK, NXP, D_INNER / KSPLIT, D_INNER, o0, nullptr);
}

// ---------------------------------------------------------------------------
// FUSED x_proj split-K reduce + dt_proj GEMM + softplus (replaces
// xproj_post + k_dtproj; kills one launch and the dtlr global round-trip).
// grid = 32 blocks (128 tokens each), 256 threads (4 waves).
// Phase A: sum 8 f32 partials -> dtlr tile in LDS (bf16) + B/C (global f32).
// Phase B: dt[128][2048] = softplus(dtlr @ dtw^T + bias), K=64 MFMA,
//          B-tile staged per 128-col chunk. LDS rows padded to 72 bf16
//          (144 B, 16B-aligned, 2-way max bank aliasing = free).
// ---------------------------------------------------------------------------
__global__ __launch_bounds__(256) void k_dtfuse(
    const float* __restrict__ partials,   // [8][T_TOK][96]
    const bf16*  __restrict__ dtw,        // [2048][64] bf16
    const float* __restrict__ dtbias,     // [2048] f32
    float* __restrict__ Bbuf, float* __restrict__ Cbuf,
    bf16* __restrict__ dtb)
{
  __shared__ __align__(16) bf16 Al[128 * 72];   // 18 KB (dtlr tile)
  __shared__ __align__(16) bf16 Bl[128 * 72];   // 18 KB (dtw tile)
  const int tid = threadIdx.x;
  const int r0  = blockIdx.x * 128;

  // ---- phase A: reduce partials ----
  #pragma unroll
  for (int it = 0; it < 12; ++it) {
    int idx = it * 256 + tid;            // over 128 rows x 24 f32x4 groups
    int row = idx / 24;
    int g   = idx - row * 24;
    f32x4 s = {0.0f, 0.0f, 0.0f, 0.0f};
    #pragma unroll
    for (int kz = 0; kz < KSPLIT; ++kz)
      s += *(const f32x4*)(partials + ((size_t)kz * T_TOK + r0 + row) * NXP + g * 4);
    if (g < 16) {                        // dt_lowrank -> LDS bf16
      bf16x4 o;
      #pragma unroll
      for (int k = 0; k < 4; ++k) o[k] = f2s(s[k]);
      *(bf16x4*)(Al + row * 72 + g * 4) = o;
    } else if (g < 20) {
      *(f32x4*)(Bbuf + (size_t)(r0 + row) * D_STATE + (g - 16) * 4) = s;
    } else {
      *(f32x4*)(Cbuf + (size_t)(r0 + row) * D_STATE + (g - 20) * 4) = s;
    }
  }
  __syncthreads();

  // ---- phase B: dt_proj GEMM ----
  const int wave = tid >> 6;
  const int lane = tid & 63;
  const int wm = (wave >> 1) * 64;
  const int wn = (wave & 1) * 64;
  const int fr = lane & 15;
  const int fk = (lane >> 4) * 8;
  const int er = (lane >> 4) * 4;
  const int ec = lane & 15;

  for (int bn = 0; bn < D_INNER; bn += 128) {
    // stage dtw tile [128][64] -> Bl
    #pragma unroll
    for (int it = 0; it < 4; ++it) {
      int idx = it * 256 + tid;          // 1024 bf16x8 groups
      int row = idx >> 3;
      int cv  = (idx & 7) * 8;
      *(bf16x8*)(Bl + row * 72 + cv) = *(const bf16x8*)(dtw + (size_t)(bn + row) * 64 + cv);
    }
    __syncthreads();

    f32x4 acc[4][4];
    #pragma unroll
    for (int i = 0; i < 4; ++i)
      #pragma unroll
      for (int j = 0; j < 4; ++j)
        #pragma unroll
        for (int r = 0; r < 4; ++r) acc[i][j][r] = 0.0f;

    #pragma unroll
    for (int k0 = 0; k0 < 64; k0 += 32) {
      bf16x8 af[4], bg[4];
      #pragma unroll
      for (int mi = 0; mi < 4; ++mi)
        af[mi] = *(const bf16x8*)(Al + (wm + mi * 16 + fr) * 72 + k0 + fk);
      #pragma unroll
      for (int ni = 0; ni < 4; ++ni)
        bg[ni] = *(const bf16x8*)(Bl + (wn + ni * 16 + fr) * 72 + k0 + fk);
      #pragma unroll
      for (int mi = 0; mi < 4; ++mi)
        #pragma unroll
        for (int ni = 0; ni < 4; ++ni)
          acc[mi][ni] = __builtin_amdgcn_mfma_f32_16x16x32_bf16(af[mi], bg[ni], acc[mi][ni], 0, 0, 0);
    }

    #pragma unroll
    for (int mi = 0; mi < 4; ++mi) {
      #pragma unroll
      for (int ni = 0; ni < 4; ++ni) {
        #pragma unroll
        for (int r = 0; r < 4; ++r) {
          int orow = r0 + wm + mi * 16 + er + r;
          int ocol = bn + wn + ni * 16 + ec;
          float v = acc[mi][ni][r] + dtbias[ocol];
          float sp = (v > 15.0f) ? v : __logf(1.0f + __expf(v));
          dtb[(size_t)orow * D_INNER + ocol] = f2bf(sp);
        }
      }
    }
    __syncthreads();
  }
}

// ---------------------------------------------------------------------------
// depthwise causal conv (W=4) + bias + SiLU, x4-vectorized over d.
// ---------------------------------------------------------------------------
__global__ void conv_silu_kernel(const bf16* __restrict__ u_pre,
                                 const float* __restrict__ cw,
                                 const float* __restrict__ cb,
                                 bf16* __restrict__ uc_bf)
{
  int idx = blockIdx.x * 256 + threadIdx.x;       // over T_TOK * D_INNER / 4
  int d4 = (idx * 4) & (D_INNER - 1);
  int t  = (idx * 4) >> 11;
  int l  = t & (L_SEQ - 1);
  float4 bias = *(const float4*)(cb + d4);
  float acc[4] = {bias.x, bias.y, bias.z, bias.w};
  float4 wv[4];
  #pragma unroll
  for (int i = 0; i < 4; ++i) wv[i] = *(const float4*)(cw + (d4 + i) * 4);
  #pragma unroll
  for (int w = 0; w < 4; ++w) {
    if (l - 3 + w >= 0) {
      bf16x4 u = *(const bf16x4*)(u_pre + (size_t)(t - 3 + w) * D_INNER + d4);
      float uf[4];
      #pragma unroll
      for (int i = 0; i < 4; ++i) { short su = u[i]; uf[i] = s2f(su); }
      acc[0] += uf[0] * ((const float*)&wv[0])[w];
      acc[1] += uf[1] * ((const float*)&wv[1])[w];
      acc[2] += uf[2] * ((const float*)&wv[2])[w];
      acc[3] += uf[3] * ((const float*)&wv[3])[w];
    }
  }
  bf16x4 out;
  #pragma unroll
  for (int i = 0; i < 4; ++i) out[i] = f2s(acc[i] * sigmoidf_(acc[i]));
  *(bf16x4*)(uc_bf + (size_t)t * D_INNER + d4) = out;
}

// ---------------------------------------------------------------------------
// helpers for the scan kernels
// ---------------------------------------------------------------------------
DEV void load_Ad(const float* A_log, int d, float* Ad, bool& fast) {
  fast = true;
  #pragma unroll
  for (int n = 0; n < 16; ++n) {
    Ad[n] = -__expf(A_log[d * 16 + n]);
    fast = fast && (fabsf(Ad[n] + (float)(n + 1)) < 1e-3f * (n + 1));
  }
}
DEV void compute_decay(bool fast, float dtv, const float* Ad, float* dec) {
  if (fast) {                       // A_n = -(n+1): decay_n = exp(-dt)^(n+1)
    float e1 = __expf(-dtv);
    float en = e1;
    #pragma unroll
    for (int n = 0; n < 16; ++n) { dec[n] = en; en *= e1; }
  } else {
    #pragma unroll
    for (int n = 0; n < 16; ++n) dec[n] = __expf(Ad[n] * dtv);
  }
}

// ---------------------------------------------------------------------------
// Scan pass 1: per-(b,chunk,d) local scan from h=0 -> chunk-end state + sum(dt)
// ---------------------------------------------------------------------------
__global__ __launch_bounds__(256) void scan_pass1(
    const bf16* __restrict__ dt, const bf16* __restrict__ uc_bf,
    const float* __restrict__ Bbuf, const float* __restrict__ A_log,
    float* __restrict__ hend, float* __restrict__ sumdt)
{
  __shared__ float Bs4[LC * D_STATE];         // 4 KB
  __shared__ bf16 dts[16 * 256];              // 8 KB
  __shared__ bf16 uts[16 * 256];              // 8 KB
  int bid = blockIdx.x;
  int tid = threadIdx.x;
  int dt8 = bid & 7;
  int c = (bid >> 3) & (NC - 1);
  int b = bid >> 8;
  int d0 = dt8 * 256;
  int d  = d0 + tid;
  int t0g = b * L_SEQ + c * LC;

  ((f32x4*)Bs4)[tid] = ((const f32x4*)(Bbuf + (size_t)t0g * D_STATE))[tid];

  float Ad[16], h[16];
  bool fast;
  load_Ad(A_log, d, Ad, fast);
  #pragma unroll
  for (int n = 0; n < 16; ++n) h[n] = 0.0f;
  float sdt = 0.0f;

  for (int sub = 0; sub < 4; ++sub) {
    __syncthreads();
    #pragma unroll
    for (int rep = 0; rep < 2; ++rep) {
      int idx = rep * 256 + tid;
      int row = idx >> 5;
      int col = (idx & 31) * 8;
      size_t src = (size_t)(t0g + sub * 16 + row) * D_INNER + d0 + col;
      *(bf16x8*)(dts + row * 256 + col) = *(const bf16x8*)(dt + src);
      *(bf16x8*)(uts + row * 256 + col) = *(const bf16x8*)(uc_bf + src);
    }
    __syncthreads();
    for (int t = 0; t < 16; ++t) {
      float dtv = bf2f(dts[t * 256 + tid]);
      float uv  = bf2f(uts[t * 256 + tid]);
      float su  = dtv * uv;
      sdt += dtv;
      float dec[16];
      compute_decay(fast, dtv, Ad, dec);
      const float* Bp = Bs4 + (sub * 16 + t) * 16;
      #pragma unroll
      for (int n = 0; n < 16; ++n)
        h[n] = h[n] * dec[n] + su * Bp[n];
    }
  }
  size_t base = ((size_t)(b * NC + c) * D_INNER + d) * 16;
  #pragma unroll
  for (int q = 0; q < 4; ++q)
    *(f32x4*)(hend + base + q * 4) = *(f32x4*)(h + q * 4);
  sumdt[(size_t)(b * NC + c) * D_INNER + d] = sdt;
}

// ---------------------------------------------------------------------------
// Scan pass 2: PARALLEL affine prefix scan over chunks.
// ---------------------------------------------------------------------------
__global__ __launch_bounds__(256) void scan_pass2(
    float* __restrict__ hend, const float* __restrict__ sumdt,
    const float* __restrict__ A_log)
{
  __shared__ float Ms[4][64];
  __shared__ float Es[4][64];
  int bid = blockIdx.x;                // 1024 blocks
  int tid = threadIdx.x;
  int cg   = tid >> 6;                 // 0..3
  int lane = tid & 63;
  int dloc = lane >> 4;                // 0..3
  int n    = lane & 15;
  int b     = bid >> 9;
  int d     = (bid & 511) * 4 + dloc;

  float a = -__expf(A_log[d * 16 + n]);

  float Ml[8], El[8];
  float M = 1.0f, E = 0.0f;
  #pragma unroll
  for (int j = 0; j < 8; ++j) {
    int c = cg * 8 + j;
    size_t sbase = (size_t)(b * NC + c) * D_INNER + d;
    float m = __expf(a * sumdt[sbase]);
    float e = hend[sbase * 16 + n];
    Ml[j] = M; El[j] = E;              // exclusive local prefix
    M = m * M;
    E = m * E + e;
  }
  Ms[cg][lane] = M;
  Es[cg][lane] = E;
  __syncthreads();
  float Ep = 0.0f;                     // exclusive group prefix (groups < cg)
  for (int g = 0; g < cg; ++g) {
    float Mg = Ms[g][lane], Eg = Es[g][lane];
    Ep = Mg * Ep + Eg;
  }
  #pragma unroll
  for (int j = 0; j < 8; ++j) {
    int c = cg * 8 + j;
    size_t sbase = (size_t)(b * NC + c) * D_INNER + d;
    hend[sbase * 16 + n] = Ml[j] * Ep + El[j];   // h at chunk start
  }
}

// ---------------------------------------------------------------------------
// Scan pass 3: re-scan with correct h0; y = (dot(h,C) + u*D) * silu(z) -> bf16
// ---------------------------------------------------------------------------
__global__ __launch_bounds__(256) void scan_pass3(
    const bf16* __restrict__ dt, const bf16* __restrict__ uc_bf,
    const float* __restrict__ Bbuf, const float* __restrict__ Cbuf,
    const bf16* __restrict__ z_silu, const float* __restrict__ hstart,
    const float* __restrict__ A_log, const float* __restrict__ Dw,
    bf16* __restrict__ y_bf)
{
  __shared__ float Bs4[LC * D_STATE];         // 4 KB
  __shared__ float Cs4[LC * D_STATE];         // 4 KB
  __shared__ bf16 dts[16 * 256];              // 8 KB
  __shared__ bf16 uts[16 * 256];              // 8 KB
  __shared__ bf16 zts[16 * 256];              // 8 KB
  int bid = blockIdx.x;
  int tid = threadIdx.x;
  int dt8 = bid & 7;
  int c = (bid >> 3) & (NC - 1);
  int b = bid >> 8;
  int d0 = dt8 * 256;
  int d  = d0 + tid;
  int t0g = b * L_SEQ + c * LC;

  ((f32x4*)Bs4)[tid] = ((const f32x4*)(Bbuf + (size_t)t0g * D_STATE))[tid];
  ((f32x4*)Cs4)[tid] = ((const f32x4*)(Cbuf + (size_t)t0g * D_STATE))[tid];

  float Ad[16], h[16];
  bool fast;
  load_Ad(A_log, d, Ad, fast);
  size_t base = ((size_t)(b * NC + c) * D_INNER + d) * 16;
  #pragma unroll
  for (int q = 0; q < 4; ++q)
    *(f32x4*)(h + q * 4) = *(const f32x4*)(hstart + base + q * 4);
  float Dv = Dw[d];

  for (int sub = 0; sub < 4; ++sub) {
    __syncthreads();
    #pragma unroll
    for (int rep = 0; rep < 2; ++rep) {
      int idx = rep * 256 + tid;
      int row = idx >> 5;
      int col = (idx & 31) * 8;
      size_t src = (size_t)(t0g + sub * 16 + row) * D_INNER + d0 + col;
      *(bf16x8*)(dts + row * 256 + col) = *(const bf16x8*)(dt + src);
      *(bf16x8*)(uts + row * 256 + col) = *(const bf16x8*)(uc_bf + src);
      *(bf16x8*)(zts + row * 256 + col) = *(const bf16x8*)(z_silu + src);
    }
    __syncthreads();
    for (int t = 0; t < 16; ++t) {
      float dtv = bf2f(dts[t * 256 + tid]);
      float uv  = bf2f(uts[t * 256 + tid]);
      float zv  = bf2f(zts[t * 256 + tid]);
      float su  = dtv * uv;
      float dec[16];
      compute_decay(fast, dtv, Ad, dec);
      const float* Bp = Bs4 + (sub * 16 + t) * 16;
      const float* Cp = Cs4 + (sub * 16 + t) * 16;
      float y = 0.0f;
      #pragma unroll
      for (int n = 0; n < 16; ++n) {
        h[n] = h[n] * dec[n] + su * Bp[n];
        y += h[n] * Cp[n];
      }
      y = (y + uv * Dv) * zv;
      y_bf[(size_t)(t0g + sub * 16 + t) * D_INNER + d] = f2bf(y);
    }
  }
}

// ---------------------------------------------------------------------------
// LayerNorm; fuses out_proj split-K=4 reduce (bf16 partials) + residual.
// ---------------------------------------------------------------------------
__global__ void ln_kernel(const bf16* __restrict__ partsA,
                          const bf16* __restrict__ partsB,
                          const bf16* __restrict__ x_bf,
                          const float* __restrict__ w,
                          const float* __restrict__ bia,
                          void* __restrict__ out,
                          const unsigned short* __restrict__ probe)
{
  int t = blockIdx.x;
  int tid = threadIdx.x;
  const bf16* p0 = partsA + (size_t)t * D_MODEL;
  const bf16* p1 = partsA + ((size_t)T_TOK + t) * D_MODEL;
  const bf16* p2 = partsB + (size_t)t * D_MODEL;
  const bf16* p3 = partsB + ((size_t)T_TOK + t) * D_MODEL;
  const bf16* xr = x_bf + (size_t)t * D_MODEL;
  float v[4];
  float s = 0.0f, q = 0.0f;
  #pragma unroll
  for (int k = 0; k < 4; ++k) {
    int col = tid + k * 256;
    v[k] = bf2f(p0[col]) + bf2f(p1[col]) + bf2f(p2[col]) + bf2f(p3[col]) + bf2f(xr[col]);
    s += v[k]; q += v[k] * v[k];
  }
  #pragma unroll
  for (int off = 32; off >= 1; off >>= 1) {
    s += __shfl_down(s, off);
    q += __shfl_down(q, off);
  }
  __shared__ float red[8];
  __shared__ float mv[2];
  int wave = tid >> 6, lane = tid & 63;
  if (lane == 0) { red[wave] = s; red[4 + wave] = q; }
  __syncthreads();
  if (tid == 0) {
    float S = red[0] + red[1] + red[2] + red[3];
    float Q = red[4] + red[5] + red[6] + red[7];
    float mu = S * (1.0f / D_MODEL);
    float var = Q * (1.0f / D_MODEL) - mu * mu;
    mv[0] = mu; mv[1] = rsqrtf(var + 1e-5f);
  }
  __syncthreads();
  float mu = mv[0], rs = mv[1];
  bool isf32 = probe_f32(probe);
  #pragma unroll
  for (int k = 0; k < 4; ++k) {
    int col = tid + k * 256;
    float r = (v[k] - mu) * rs * w[col] + bia[col];
    if (isf32) ((float*)out)[(size_t)t * D_MODEL + col] = r;
    else       ((bf16*) out)[(size_t)t * D_MODEL + col] = f2bf(r);
  }
}

// ---------------------------------------------------------------------------
extern "C" void kernel_launch(void* const* d_in, const int* in_sizes, int n_in,
                              void* d_out, int out_size, void* d_ws, size_t ws_size,
                              hipStream_t stream)
{
  const void* x        = d_in[0];
  const void* in_w     = d_in[1];
  const void* conv_w   = d_in[2];
  const void* conv_b   = d_in[3];
  const void* xproj_w  = d_in[4];
  const void* dtproj_w = d_in[5];
  const void* dtproj_b = d_in[6];
  const void* A_log    = d_in[7];
  const void* Dw       = d_in[8];
  const void* out_w    = d_in[9];
  const void* ln_w     = d_in[10];
  const void* ln_b     = d_in[11];
  const unsigned short* probe = (const unsigned short*)A_log;

  char* p = (char*)d_ws;
  auto alloc = [&](size_t bytes) { char* r = p; p += (bytes + 255) & ~255ull; return r; };
  bf16*  x_bf   = (bf16*) alloc((size_t)T_TOK * D_MODEL * 2);          // 8.4 MB
  bf16*  inw_bf = (bf16*) alloc((size_t)2 * D_INNER * D_MODEL * 2);    // 8.4 MB
  bf16*  xpw_bf = (bf16*) alloc((size_t)NXP * D_INNER * 2);            // 0.4 MB
  bf16*  dtw_bf = (bf16*) alloc((size_t)D_INNER * DT_RANK * 2);        // 0.26 MB
  bf16*  outw_bf= (bf16*) alloc((size_t)D_MODEL * D_INNER * 2);        // 4.2 MB
  float* params = (float*)alloc((size_t)P_TOT * 4);                    // 0.2 MB
  bf16*  u_pre  = (bf16*) alloc((size_t)T_TOK * D_INNER * 2);          // 16.8 MB (then xparts, then y_bf)
  bf16*  z_silu = (bf16*) alloc((size_t)T_TOK * D_INNER * 2);          // 16.8 MB (then outproj partials z=0,1)
  bf16*  uc_bf  = (bf16*) alloc((size_t)T_TOK * D_INNER * 2);          // 16.8 MB
  bf16*  dtlr   = (bf16*) alloc((size_t)T_TOK * DT_RANK * 2);          // 0.5 MB (unused, kept for layout)
  float* Bbuf   = (float*)alloc((size_t)T_TOK * D_STATE * 4);          // 0.26 MB
  float* Cbuf   = (float*)alloc((size_t)T_TOK * D_STATE * 4);          // 0.26 MB
  bf16*  dtb    = (bf16*) alloc((size_t)T_TOK * D_INNER * 2);          // 16.8 MB (dt; then outproj partials z=2,3)
  float* hend   = (float*)alloc((size_t)B_SZ * NC * D_INNER * 16 * 4); // 8.4 MB
  float* sumdt  = (float*)alloc((size_t)B_SZ * NC * D_INNER * 4);      // 0.5 MB
  (void)dtlr;
  bf16*  y_bf   = u_pre;            // u_pre dead after conv; xparts dead after dtfuse
  float* xparts = (float*)u_pre;    // u_pre dead after conv; 12.6 MB <= 16.8 MB
  bf16*  opartsA = z_silu;          // z dead after pass3
  bf16*  opartsB = dtb;             // dt dead after pass3

  dim3 blk(256);
  dim3 blk512(512);
  // 0) normalize ALL inputs in one launch (dtype-agnostic, vectorized)
  cvt_all<<<5304, blk, 0, stream>>>(x, in_w, xproj_w, dtproj_w, out_w,
                                    conv_w, conv_b, dtproj_b, A_log, Dw, ln_w, ln_b,
                                    x_bf, inw_bf, xpw_bf, dtw_bf, outw_bf, params, probe);

  // 1) in_proj (BM=BN=256, BK=64, 2-slot ring, counted vmcnt, XCD swizzle)
  k_inproj<<<dim3(T_TOK / 256, (2 * D_INNER) / 256), blk512, 0, stream>>>(x_bf, inw_bf, u_pre, z_silu);
  // 2) causal depthwise conv + bias + silu -> uc_bf (x4 vectorized)
  conv_silu_kernel<<<(T_TOK * D_INNER) / 1024, blk, 0, stream>>>(u_pre, params + P_CONVW, params + P_CONVB, uc_bf);
  // 3) x_proj split-K (register staging) -> f32 partials (in dead u_pre)
  k_xproj<<<dim3(T_TOK / 128, 1, KSPLIT), blk, 0, stream>>>(uc_bf, xpw_bf, xparts);
  // 4) FUSED partial-reduce + dt_proj + softplus -> Bbuf/Cbuf/dtb
  k_dtfuse<<<T_TOK / 128, blk, 0, stream>>>(xparts, dtw_bf, params + P_DTB, Bbuf, Cbuf, dtb);
  // 5-7) chunked selective scan (pass2 parallel prefix)
  scan_pass1<<<B_SZ * NC * (D_INNER / 256), blk, 0, stream>>>(dtb, uc_bf, Bbuf, params + P_ALOG, hend, sumdt);
  scan_pass2<<<(B_SZ * D_INNER) / 2, blk, 0, stream>>>(hend, sumdt, params + P_ALOG);
  scan_pass3<<<B_SZ * NC * (D_INNER / 256), blk, 0, stream>>>(
      dtb, uc_bf, Bbuf, Cbuf, z_silu, hend, params + P_ALOG, params + P_DW, y_bf);
  // 8) out_proj split-K=4 (pipelined body, XCD swizzle) -> partials
  k_outproj<<<dim3(T_TOK / 256, D_MODEL / 256, 4), blk512, 0, stream>>>(y_bf, outw_bf, opartsA, opartsB);
  // 9) layernorm (fused 4-way bf16 split-K reduce + residual) -> d_out
  ln_kernel<<<T_TOK, blk, 0, stream>>>(opartsA, opartsB, x_bf, params + P_LNW, params + P_LNB, d_out, probe);
}

// Round 6
// 304.242 us; speedup vs baseline: 1.3450x; 1.3450x over previous
//
#include <hip/hip_runtime.h>
#include <hip/hip_bf16.h>
#include <math.h>

#define DEV static __device__ __forceinline__

typedef __hip_bfloat16 bf16;
typedef __attribute__((ext_vector_type(8))) short bf16x8;   // 8 bf16 = 4 VGPRs
typedef __attribute__((ext_vector_type(4))) short bf16x4;   // 4 bf16 = 2 VGPRs
typedef __attribute__((ext_vector_type(4))) float f32x4;

static constexpr int D_MODEL = 1024;
static constexpr int D_INNER = 2048;
static constexpr int D_STATE = 16;
static constexpr int DT_RANK = 64;
static constexpr int B_SZ   = 2;
static constexpr int L_SEQ  = 2048;
static constexpr int T_TOK  = B_SZ * L_SEQ;   // 4096 tokens
static constexpr int LC     = 64;             // scan chunk length
static constexpr int NC     = L_SEQ / LC;     // 32 chunks per sequence
static constexpr int NXP    = DT_RANK + 2 * D_STATE;   // 96
static constexpr int KSPLIT = 8;              // x_proj split-K factor

// params (f32) layout inside ws
static constexpr int P_CONVW = 0;        // [2048*4]
static constexpr int P_CONVB = 8192;     // [2048]
static constexpr int P_DTB   = 10240;    // [2048]
static constexpr int P_ALOG  = 12288;    // [2048*16]
static constexpr int P_DW    = 45056;    // [2048]
static constexpr int P_LNW   = 47104;    // [1024]
static constexpr int P_LNB   = 48128;    // [1024]
static constexpr int P_TOT   = 49152;

DEV float bf2f(bf16 x) { return __bfloat162float(x); }
DEV bf16  f2bf(float x) { return __float2bfloat16(x); }
DEV float sigmoidf_(float x) { return 1.0f / (1.0f + __expf(-x)); }
DEV float s2f(short s) { bf16 b; __builtin_memcpy(&b, &s, 2); return bf2f(b); }
DEV short f2s(float x) { bf16 b = f2bf(x); short s; __builtin_memcpy(&s, &b, 2); return s; }

DEV bool probe_f32(const unsigned short* probe) { return probe[1] == 0; }

DEV void async_copy16(const void* g, void* l) {
  // DMA 16 B/lane: LDS dest = wave-uniform base + lane*16 (m97-verified)
  __builtin_amdgcn_global_load_lds(
      (const __attribute__((address_space(1))) void*)g,
      (__attribute__((address_space(3))) void*)l, 16, 0, 0);
}

template <int N>
DEV void vm_wait() {
  if constexpr (N == 8)      asm volatile("s_waitcnt vmcnt(8)" ::: "memory");
  else if constexpr (N == 6) asm volatile("s_waitcnt vmcnt(6)" ::: "memory");
  else                       asm volatile("s_waitcnt vmcnt(0)" ::: "memory");
}

// ---------------------------------------------------------------------------
// fused input normalization: ALL 12 tensors in one launch (8 elems/thread,
// vectorized stores).
// ---------------------------------------------------------------------------
__global__ void cvt_all(const void* s0, const void* s1, const void* s2,
                        const void* s3, const void* s4,
                        const void* s5, const void* s6, const void* s7,
                        const void* s8, const void* s9, const void* s10,
                        const void* s11,
                        bf16* d0, bf16* d1, bf16* d2, bf16* d3, bf16* d4,
                        float* params,
                        const unsigned short* __restrict__ probe)
{
  long i = (long)(blockIdx.x * 256 + threadIdx.x) * 8;
  const void* src; long off;
  bf16* dstb = nullptr; float* dstf = nullptr;
  if      (i <  4194304) { src = s0;  dstb = d0; off = i; }
  else if (i <  8388608) { src = s1;  dstb = d1; off = i - 4194304; }
  else if (i <  8585216) { src = s2;  dstb = d2; off = i - 8388608; }
  else if (i <  8716288) { src = s3;  dstb = d3; off = i - 8585216; }
  else if (i < 10813440) { src = s4;  dstb = d4; off = i - 8716288; }
  else if (i < 10821632) { src = s5;  dstf = params + P_CONVW; off = i - 10813440; }
  else if (i < 10823680) { src = s6;  dstf = params + P_CONVB; off = i - 10821632; }
  else if (i < 10825728) { src = s7;  dstf = params + P_DTB;   off = i - 10823680; }
  else if (i < 10858496) { src = s8;  dstf = params + P_ALOG;  off = i - 10825728; }
  else if (i < 10860544) { src = s9;  dstf = params + P_DW;    off = i - 10858496; }
  else if (i < 10861568) { src = s10; dstf = params + P_LNW;   off = i - 10860544; }
  else if (i < 10862592) { src = s11; dstf = params + P_LNB;   off = i - 10861568; }
  else return;
  bool isf32 = probe_f32(probe);
  float v[8];
  if (isf32) {
    float4 a = *(const float4*)((const float*)src + off);
    float4 b = *(const float4*)((const float*)src + off + 4);
    v[0]=a.x; v[1]=a.y; v[2]=a.z; v[3]=a.w;
    v[4]=b.x; v[5]=b.y; v[6]=b.z; v[7]=b.w;
  } else {
    bf16x8 t = *(const bf16x8*)((const bf16*)src + off);
    #pragma unroll
    for (int k = 0; k < 8; ++k) { short sk = t[k]; v[k] = s2f(sk); }
  }
  if (dstb) {
    bf16x8 o;
    #pragma unroll
    for (int k = 0; k < 8; ++k) o[k] = f2s(v[k]);
    *(bf16x8*)(dstb + off) = o;
  } else {
    f32x4 a = {v[0], v[1], v[2], v[3]};
    f32x4 b = {v[4], v[5], v[6], v[7]};
    *(f32x4*)(dstf + off)     = a;
    *(f32x4*)(dstf + off + 4) = b;
  }
}

// ---------------------------------------------------------------------------
// 8-wave pipelined GEMM: BM=BN=256, BK=64, wave tile 128x64 (2M x 4N).
// LDS 2-slot ring (128 KiB), counted vmcnt(8) per tile, compiler-scheduled
// core, 128B LDS rows + 8-chunk XOR swizzle (0 bank conflicts).
// XCD-chunked blockIdx swizzle (T1, bijective: nwg%8==0).
// MODE 0: in_proj  -> o0=u_pre bf16, o1=silu(z) bf16
// MODE 3: out_proj split-K=4 -> bf16 partials z0,1->o0, z2,3->o1
// ---------------------------------------------------------------------------
DEV void stage256(const bf16* __restrict__ src, int ld, int base_row, int k0,
                  char* dst_base, int tid) {
  #pragma unroll
  for (int j = 0; j < 4; ++j) {
    int p   = j * 8192 + tid * 16;           // linear LDS dest byte
    int row = p >> 7;                        // 0..255 (128B rows)
    int ck  = ((p >> 4) & 7) ^ (row & 7);    // inverse-swizzled 16B chunk
    async_copy16(src + (size_t)(base_row + row) * ld + k0 + ck * 8,
                 dst_base + j * 8192 + (tid >> 6) * 1024);
  }
}

template <int MODE>
DEV void gemm_pipe256(const bf16* __restrict__ A, const bf16* __restrict__ B,
                      int M, int K, int ld,
                      void* __restrict__ o0, void* __restrict__ o1)
{
  __shared__ __align__(16) char ring[2 * 65536];   // 128 KiB

  // XCD-chunked bijective swizzle over the full linear grid
  unsigned lin = blockIdx.x + gridDim.x * (blockIdx.y + gridDim.y * blockIdx.z);
  unsigned nwg = gridDim.x * gridDim.y * gridDim.z;
  unsigned cpx = nwg >> 3;                 // nwg % 8 == 0 by construction
  unsigned nid = (lin & 7) * cpx + (lin >> 3);
  unsigned bx  = nid % gridDim.x;
  unsigned tq  = nid / gridDim.x;
  unsigned by  = tq % gridDim.y;
  unsigned bz  = tq / gridDim.y;

  if (MODE == 3) {
    A += (size_t)bz * K;
    B += (size_t)bz * K;
  }
  const int tid  = threadIdx.x;
  const int wave = tid >> 6;
  const int lane = tid & 63;
  const int bm = bx * 256;
  const int bn = by * 256;
  const int wmr = (wave >> 2) * 128;     // 0/128: A row group (128 rows)
  const int wnr = (wave & 3) * 64;       // 0..192: B row group (64 rows)
  const int fr = lane & 15;
  const int fq = lane >> 4;              // 0..3
  const int frs = lane & 7;
  const int NT = K / 64;

  f32x4 acc[8][4];
  #pragma unroll
  for (int i = 0; i < 8; ++i)
    #pragma unroll
    for (int j = 0; j < 4; ++j)
      #pragma unroll
      for (int r = 0; r < 4; ++r) acc[i][j][r] = 0.0f;

  // prologue: stage tiles 0 and 1 (16 loads/thread in flight)
  stage256(A, ld, bm, 0,  ring,                 tid);
  stage256(B, ld, bn, 0,  ring + 32768,         tid);
  stage256(A, ld, bm, 64, ring + 65536,         tid);
  stage256(B, ld, bn, 64, ring + 65536 + 32768, tid);

  #pragma unroll 1
  for (int tk = 0; tk < NT; ++tk) {
    // tile tk's 8 loads are oldest; tile tk+1's 8 may stay in flight
    if (tk < NT - 1) vm_wait<8>();
    else             vm_wait<0>();
    __builtin_amdgcn_s_barrier();

    const char* sa = ring + (size_t)(tk & 1) * 65536;

    // B fragments (8 ds_read_b128) — compiler schedules waits
    bf16x8 bg[4][2];
    #pragma unroll
    for (int ni = 0; ni < 4; ++ni)
      #pragma unroll
      for (int kk = 0; kk < 2; ++kk)
        bg[ni][kk] = *(const bf16x8*)(sa + 32768
                       + (size_t)(wnr + ni * 16 + fr) * 128
                       + (((kk * 4 + fq) ^ frs) * 16));

    __builtin_amdgcn_s_setprio(1);
    #pragma unroll
    for (int mh = 0; mh < 2; ++mh) {
      bf16x8 af[4][2];
      #pragma unroll
      for (int mi = 0; mi < 4; ++mi)
        #pragma unroll
        for (int kk = 0; kk < 2; ++kk)
          af[mi][kk] = *(const bf16x8*)(sa
                         + (size_t)(wmr + mh * 64 + mi * 16 + fr) * 128
                         + (((kk * 4 + fq) ^ frs) * 16));
      #pragma unroll
      for (int kk = 0; kk < 2; ++kk)
        #pragma unroll
        for (int mi = 0; mi < 4; ++mi)
          #pragma unroll
          for (int ni = 0; ni < 4; ++ni)
            acc[mh * 4 + mi][ni] = __builtin_amdgcn_mfma_f32_16x16x32_bf16(
                af[mi][kk], bg[ni][kk], acc[mh * 4 + mi][ni], 0, 0, 0);
    }
    __builtin_amdgcn_s_setprio(0);

    // all reads already consumed -> ~free, but makes the stage below
    // provably WAR-safe across the barrier.
    asm volatile("s_waitcnt lgkmcnt(0)" ::: "memory");
    __builtin_amdgcn_s_barrier();
    if (tk + 2 < NT) {
      char* sn = ring + (size_t)(tk & 1) * 65536;
      stage256(A, ld, bm, (tk + 2) * 64, sn,         tid);
      stage256(B, ld, bn, (tk + 2) * 64, sn + 32768, tid);
    }
  }

  const int er = (lane >> 4) * 4;     // C/D: row = er + reg, col = lane&15
  const int ec = lane & 15;
  #pragma unroll
  for (int ai = 0; ai < 8; ++ai) {
    #pragma unroll
    for (int ni = 0; ni < 4; ++ni) {
      #pragma unroll
      for (int r = 0; r < 4; ++r) {
        int row = bm + wmr + ai * 16 + er + r;   // token index
        int col = bn + wnr + ni * 16 + ec;
        float v = acc[ai][ni][r];
        if (MODE == 0) {
          if (col < D_INNER) ((bf16*)o0)[(size_t)row * D_INNER + col] = f2bf(v);
          else               ((bf16*)o1)[(size_t)row * D_INNER + (col - D_INNER)] = f2bf(v * sigmoidf_(v));
        } else {
          bf16* dst = (bz < 2) ? (bf16*)o0 : (bf16*)o1;
          dst[(((size_t)(bz & 1)) * M + row) * D_MODEL + col] = f2bf(v);
        }
      }
    }
  }
}

// ---------------------------------------------------------------------------
// BK=32 register-staged GEMM body (x_proj split-K -> f32 partials)
// ---------------------------------------------------------------------------
template <int MODE>
DEV void gemm_body32(const bf16* __restrict__ A, const bf16* __restrict__ B,
                     int M, int N, int K, int ld,
                     void* __restrict__ o0, const void* __restrict__ e0)
{
  __shared__ __align__(16) bf16 As[128 * 32];
  __shared__ __align__(16) bf16 Bs[128 * 32];
  if (MODE == 1) {
    A += (size_t)blockIdx.z * K;
    B += (size_t)blockIdx.z * K;
  }
  const int tid  = threadIdx.x;
  const int wave = tid >> 6;
  const int lane = tid & 63;
  const int bm = blockIdx.x * 128;
  const int bn = blockIdx.y * 128;
  const int wm = (wave >> 1) * 64;
  const int wn = (wave & 1) * 64;

  f32x4 acc[4][4];
  #pragma unroll
  for (int i = 0; i < 4; ++i)
    #pragma unroll
    for (int j = 0; j < 4; ++j)
      #pragma unroll
      for (int r = 0; r < 4; ++r) acc[i][j][r] = 0.0f;

  const int ar0 = tid >> 2;
  const int ar1 = ar0 + 64;
  const int ac  = (tid & 3) * 8;
  const int fr = lane & 15;
  const int fk = (lane >> 4) * 8;

  for (int k0 = 0; k0 < K; k0 += 32) {
    bf16x8 a0 = *(const bf16x8*)(A + (size_t)(bm + ar0) * ld + k0 + ac);
    bf16x8 a1 = *(const bf16x8*)(A + (size_t)(bm + ar1) * ld + k0 + ac);
    int r0 = bn + ar0; if (r0 > N - 1) r0 = N - 1;
    int r1 = bn + ar1; if (r1 > N - 1) r1 = N - 1;
    bf16x8 b0 = *(const bf16x8*)(B + (size_t)r0 * ld + k0 + ac);
    bf16x8 b1 = *(const bf16x8*)(B + (size_t)r1 * ld + k0 + ac);
    __syncthreads();
    *(bf16x8*)(As + ar0 * 32 + ac) = a0;
    *(bf16x8*)(As + ar1 * 32 + ac) = a1;
    *(bf16x8*)(Bs + ar0 * 32 + ac) = b0;
    *(bf16x8*)(Bs + ar1 * 32 + ac) = b1;
    __syncthreads();

    bf16x8 af[4], bg[4];
    #pragma unroll
    for (int mi = 0; mi < 4; ++mi)
      af[mi] = *(const bf16x8*)(As + (wm + mi * 16 + fr) * 32 + fk);
    #pragma unroll
    for (int ni = 0; ni < 4; ++ni)
      bg[ni] = *(const bf16x8*)(Bs + (wn + ni * 16 + fr) * 32 + fk);
    #pragma unroll
    for (int mi = 0; mi < 4; ++mi)
      #pragma unroll
      for (int ni = 0; ni < 4; ++ni)
        acc[mi][ni] = __builtin_amdgcn_mfma_f32_16x16x32_bf16(af[mi], bg[ni], acc[mi][ni], 0, 0, 0);
  }

  const int er = (lane >> 4) * 4;
  const int ec = lane & 15;
  #pragma unroll
  for (int mi = 0; mi < 4; ++mi) {
    #pragma unroll
    for (int ni = 0; ni < 4; ++ni) {
      #pragma unroll
      for (int r = 0; r < 4; ++r) {
        int row = bm + wm + mi * 16 + er + r;
        int col = bn + wn + ni * 16 + ec;
        if (col >= N) continue;
        float v = acc[mi][ni][r];
        ((float*)o0)[((size_t)blockIdx.z * M + row) * N + col] = v;
      }
    }
  }
}

// distinct names so rocprof disambiguates the stages
__global__ void __launch_bounds__(512, 2) k_inproj(const bf16* A, const bf16* B,
    void* o0, void* o1) {
  gemm_pipe256<0>(A, B, T_TOK, D_MODEL, D_MODEL, o0, o1);
}
__global__ void __launch_bounds__(512, 2) k_outproj(const bf16* A, const bf16* B,
    void* o0, void* o1) {
  gemm_pipe256<3>(A, B, T_TOK, D_INNER / 4, D_INNER, o0, o1);
}
__global__ void __launch_bounds__(256) k_xproj(const bf16* A, const bf16* B,
    void* o0) {
  gemm_body32<1>(A, B, T_TOK, NXP, D_INNER / KSPLIT, D_INNER, o0, nullptr);
}

// ---------------------------------------------------------------------------
// FUSED x_proj split-K reduce + dt_proj GEMM + softplus — round-6 fix:
// grid = (16 col-blocks x 32 token-blocks) = 512 blocks (full GPU), each
// block reduces its OWN 128x64 dtlr tile (redundant across col-blocks, but
// XCD-chunked swizzle puts all 16 col-blocks of a token slab on ONE XCD so
// 15/16 re-reads are L2 hits; slab partials = 1.6 MB << 4 MB L2/XCD) and
// computes one 128x128 K=64 MFMA GEMM + softplus. col-block 0 writes B/C.
// ---------------------------------------------------------------------------
__global__ __launch_bounds__(256) void k_dtfuse(
    const float* __restrict__ partials,   // [8][T_TOK][96]
    const bf16*  __restrict__ dtw,        // [2048][64] bf16
    const float* __restrict__ dtbias,     // [2048] f32
    float* __restrict__ Bbuf, float* __restrict__ Cbuf,
    bf16* __restrict__ dtb)
{
  __shared__ __align__(16) bf16 Al[128 * 72];   // 18 KB (dtlr tile, pad 72)
  __shared__ __align__(16) bf16 Bl[128 * 72];   // 18 KB (dtw tile)
  const int tid = threadIdx.x;
  // XCD-chunked swizzle: grid (16,32); col index fastest in nid
  unsigned lin = blockIdx.x + gridDim.x * blockIdx.y;
  unsigned nid = (lin & 7) * 64 + (lin >> 3);   // nwg=512, cpx=64
  const int cblk = nid & 15;
  const int tblk = nid >> 4;
  const int r0 = tblk * 128;
  const int c0 = cblk * 128;

  // ---- phase A: reduce dt columns (groups 0..15) into Al ----
  #pragma unroll
  for (int it = 0; it < 8; ++it) {
    int idx = it * 256 + tid;            // 128 rows x 16 f32x4 groups
    int row = idx >> 4;
    int g   = idx & 15;
    f32x4 s = {0.0f, 0.0f, 0.0f, 0.0f};
    #pragma unroll
    for (int kz = 0; kz < KSPLIT; ++kz)
      s += *(const f32x4*)(partials + ((size_t)kz * T_TOK + r0 + row) * NXP + g * 4);
    bf16x4 o;
    #pragma unroll
    for (int k = 0; k < 4; ++k) o[k] = f2s(s[k]);
    *(bf16x4*)(Al + row * 72 + g * 4) = o;
  }
  // col-block 0 also reduces + writes B/C (groups 16..23)
  if (cblk == 0) {
    #pragma unroll
    for (int it = 0; it < 4; ++it) {
      int idx = it * 256 + tid;          // 128 rows x 8 groups
      int row = idx >> 3;
      int g   = 16 + (idx & 7);
      f32x4 s = {0.0f, 0.0f, 0.0f, 0.0f};
      #pragma unroll
      for (int kz = 0; kz < KSPLIT; ++kz)
        s += *(const f32x4*)(partials + ((size_t)kz * T_TOK + r0 + row) * NXP + g * 4);
      if (g < 20) *(f32x4*)(Bbuf + (size_t)(r0 + row) * D_STATE + (g - 16) * 4) = s;
      else        *(f32x4*)(Cbuf + (size_t)(r0 + row) * D_STATE + (g - 20) * 4) = s;
    }
  }
  // stage dtw tile [128][64] -> Bl (independent of phase A)
  #pragma unroll
  for (int it = 0; it < 4; ++it) {
    int idx = it * 256 + tid;            // 1024 bf16x8 groups
    int row = idx >> 3;
    int cv  = (idx & 7) * 8;
    *(bf16x8*)(Bl + row * 72 + cv) = *(const bf16x8*)(dtw + (size_t)(c0 + row) * 64 + cv);
  }
  __syncthreads();

  // ---- phase B: 128x128 K=64 GEMM + softplus ----
  const int wave = tid >> 6;
  const int lane = tid & 63;
  const int wm = (wave >> 1) * 64;
  const int wn = (wave & 1) * 64;
  const int fr = lane & 15;
  const int fk = (lane >> 4) * 8;
  const int er = (lane >> 4) * 4;
  const int ec = lane & 15;

  f32x4 acc[4][4];
  #pragma unroll
  for (int i = 0; i < 4; ++i)
    #pragma unroll
    for (int j = 0; j < 4; ++j)
      #pragma unroll
      for (int r = 0; r < 4; ++r) acc[i][j][r] = 0.0f;

  #pragma unroll
  for (int k0 = 0; k0 < 64; k0 += 32) {
    bf16x8 af[4], bg[4];
    #pragma unroll
    for (int mi = 0; mi < 4; ++mi)
      af[mi] = *(const bf16x8*)(Al + (wm + mi * 16 + fr) * 72 + k0 + fk);
    #pragma unroll
    for (int ni = 0; ni < 4; ++ni)
      bg[ni] = *(const bf16x8*)(Bl + (wn + ni * 16 + fr) * 72 + k0 + fk);
    #pragma unroll
    for (int mi = 0; mi < 4; ++mi)
      #pragma unroll
      for (int ni = 0; ni < 4; ++ni)
        acc[mi][ni] = __builtin_amdgcn_mfma_f32_16x16x32_bf16(af[mi], bg[ni], acc[mi][ni], 0, 0, 0);
  }

  #pragma unroll
  for (int mi = 0; mi < 4; ++mi) {
    #pragma unroll
    for (int ni = 0; ni < 4; ++ni) {
      #pragma unroll
      for (int r = 0; r < 4; ++r) {
        int orow = r0 + wm + mi * 16 + er + r;
        int ocol = c0 + wn + ni * 16 + ec;
        float v = acc[mi][ni][r] + dtbias[ocol];
        float sp = (v > 15.0f) ? v : __logf(1.0f + __expf(v));
        dtb[(size_t)orow * D_INNER + ocol] = f2bf(sp);
      }
    }
  }
}

// ---------------------------------------------------------------------------
// depthwise causal conv (W=4) + bias + SiLU, x4-vectorized over d.
// ---------------------------------------------------------------------------
__global__ void conv_silu_kernel(const bf16* __restrict__ u_pre,
                                 const float* __restrict__ cw,
                                 const float* __restrict__ cb,
                                 bf16* __restrict__ uc_bf)
{
  int idx = blockIdx.x * 256 + threadIdx.x;       // over T_TOK * D_INNER / 4
  int d4 = (idx * 4) & (D_INNER - 1);
  int t  = (idx * 4) >> 11;
  int l  = t & (L_SEQ - 1);
  float4 bias = *(const float4*)(cb + d4);
  float acc[4] = {bias.x, bias.y, bias.z, bias.w};
  float4 wv[4];
  #pragma unroll
  for (int i = 0; i < 4; ++i) wv[i] = *(const float4*)(cw + (d4 + i) * 4);
  #pragma unroll
  for (int w = 0; w < 4; ++w) {
    if (l - 3 + w >= 0) {
      bf16x4 u = *(const bf16x4*)(u_pre + (size_t)(t - 3 + w) * D_INNER + d4);
      float uf[4];
      #pragma unroll
      for (int i = 0; i < 4; ++i) { short su = u[i]; uf[i] = s2f(su); }
      acc[0] += uf[0] * ((const float*)&wv[0])[w];
      acc[1] += uf[1] * ((const float*)&wv[1])[w];
      acc[2] += uf[2] * ((const float*)&wv[2])[w];
      acc[3] += uf[3] * ((const float*)&wv[3])[w];
    }
  }
  bf16x4 out;
  #pragma unroll
  for (int i = 0; i < 4; ++i) out[i] = f2s(acc[i] * sigmoidf_(acc[i]));
  *(bf16x4*)(uc_bf + (size_t)t * D_INNER + d4) = out;
}

// ---------------------------------------------------------------------------
// helpers for the scan kernels
// ---------------------------------------------------------------------------
DEV void load_Ad(const float* A_log, int d, float* Ad, bool& fast) {
  fast = true;
  #pragma unroll
  for (int n = 0; n < 16; ++n) {
    Ad[n] = -__expf(A_log[d * 16 + n]);
    fast = fast && (fabsf(Ad[n] + (float)(n + 1)) < 1e-3f * (n + 1));
  }
}
DEV void compute_decay(bool fast, float dtv, const float* Ad, float* dec) {
  if (fast) {                       // A_n = -(n+1): decay_n = exp(-dt)^(n+1)
    float e1 = __expf(-dtv);
    float en = e1;
    #pragma unroll
    for (int n = 0; n < 16; ++n) { dec[n] = en; en *= e1; }
  } else {
    #pragma unroll
    for (int n = 0; n < 16; ++n) dec[n] = __expf(Ad[n] * dtv);
  }
}

// ---------------------------------------------------------------------------
// Scan pass 1: per-(b,chunk,d) local scan from h=0 -> chunk-end state + sum(dt)
// ---------------------------------------------------------------------------
__global__ __launch_bounds__(256) void scan_pass1(
    const bf16* __restrict__ dt, const bf16* __restrict__ uc_bf,
    const float* __restrict__ Bbuf, const float* __restrict__ A_log,
    float* __restrict__ hend, float* __restrict__ sumdt)
{
  __shared__ float Bs4[LC * D_STATE];         // 4 KB
  __shared__ bf16 dts[16 * 256];              // 8 KB
  __shared__ bf16 uts[16 * 256];              // 8 KB
  int bid = blockIdx.x;
  int tid = threadIdx.x;
  int dt8 = bid & 7;
  int c = (bid >> 3) & (NC - 1);
  int b = bid >> 8;
  int d0 = dt8 * 256;
  int d  = d0 + tid;
  int t0g = b * L_SEQ + c * LC;

  ((f32x4*)Bs4)[tid] = ((const f32x4*)(Bbuf + (size_t)t0g * D_STATE))[tid];

  float Ad[16], h[16];
  bool fast;
  load_Ad(A_log, d, Ad, fast);
  #pragma unroll
  for (int n = 0; n < 16; ++n) h[n] = 0.0f;
  float sdt = 0.0f;

  for (int sub = 0; sub < 4; ++sub) {
    __syncthreads();
    #pragma unroll
    for (int rep = 0; rep < 2; ++rep) {
      int idx = rep * 256 + tid;
      int row = idx >> 5;
      int col = (idx & 31) * 8;
      size_t src = (size_t)(t0g + sub * 16 + row) * D_INNER + d0 + col;
      *(bf16x8*)(dts + row * 256 + col) = *(const bf16x8*)(dt + src);
      *(bf16x8*)(uts + row * 256 + col) = *(const bf16x8*)(uc_bf + src);
    }
    __syncthreads();
    for (int t = 0; t < 16; ++t) {
      float dtv = bf2f(dts[t * 256 + tid]);
      float uv  = bf2f(uts[t * 256 + tid]);
      float su  = dtv * uv;
      sdt += dtv;
      float dec[16];
      compute_decay(fast, dtv, Ad, dec);
      const float* Bp = Bs4 + (sub * 16 + t) * 16;
      #pragma unroll
      for (int n = 0; n < 16; ++n)
        h[n] = h[n] * dec[n] + su * Bp[n];
    }
  }
  size_t base = ((size_t)(b * NC + c) * D_INNER + d) * 16;
  #pragma unroll
  for (int q = 0; q < 4; ++q)
    *(f32x4*)(hend + base + q * 4) = *(f32x4*)(h + q * 4);
  sumdt[(size_t)(b * NC + c) * D_INNER + d] = sdt;
}

// ---------------------------------------------------------------------------
// Scan pass 2: PARALLEL affine prefix scan over chunks.
// ---------------------------------------------------------------------------
__global__ __launch_bounds__(256) void scan_pass2(
    float* __restrict__ hend, const float* __restrict__ sumdt,
    const float* __restrict__ A_log)
{
  __shared__ float Ms[4][64];
  __shared__ float Es[4][64];
  int bid = blockIdx.x;                // 1024 blocks
  int tid = threadIdx.x;
  int cg   = tid >> 6;                 // 0..3
  int lane = tid & 63;
  int dloc = lane >> 4;                // 0..3
  int n    = lane & 15;
  int b     = bid >> 9;
  int d     = (bid & 511) * 4 + dloc;

  float a = -__expf(A_log[d * 16 + n]);

  float Ml[8], El[8];
  float M = 1.0f, E = 0.0f;
  #pragma unroll
  for (int j = 0; j < 8; ++j) {
    int c = cg * 8 + j;
    size_t sbase = (size_t)(b * NC + c) * D_INNER + d;
    float m = __expf(a * sumdt[sbase]);
    float e = hend[sbase * 16 + n];
    Ml[j] = M; El[j] = E;              // exclusive local prefix
    M = m * M;
    E = m * E + e;
  }
  Ms[cg][lane] = M;
  Es[cg][lane] = E;
  __syncthreads();
  float Ep = 0.0f;                     // exclusive group prefix (groups < cg)
  for (int g = 0; g < cg; ++g) {
    float Mg = Ms[g][lane], Eg = Es[g][lane];
    Ep = Mg * Ep + Eg;
  }
  #pragma unroll
  for (int j = 0; j < 8; ++j) {
    int c = cg * 8 + j;
    size_t sbase = (size_t)(b * NC + c) * D_INNER + d;
    hend[sbase * 16 + n] = Ml[j] * Ep + El[j];   // h at chunk start
  }
}

// ---------------------------------------------------------------------------
// Scan pass 3: re-scan with correct h0; y = (dot(h,C) + u*D) * silu(z) -> bf16
// ---------------------------------------------------------------------------
__global__ __launch_bounds__(256) void scan_pass3(
    const bf16* __restrict__ dt, const bf16* __restrict__ uc_bf,
    const float* __restrict__ Bbuf, const float* __restrict__ Cbuf,
    const bf16* __restrict__ z_silu, const float* __restrict__ hstart,
    const float* __restrict__ A_log, const float* __restrict__ Dw,
    bf16* __restrict__ y_bf)
{
  __shared__ float Bs4[LC * D_STATE];         // 4 KB
  __shared__ float Cs4[LC * D_STATE];         // 4 KB
  __shared__ bf16 dts[16 * 256];              // 8 KB
  __shared__ bf16 uts[16 * 256];              // 8 KB
  __shared__ bf16 zts[16 * 256];              // 8 KB
  int bid = blockIdx.x;
  int tid = threadIdx.x;
  int dt8 = bid & 7;
  int c = (bid >> 3) & (NC - 1);
  int b = bid >> 8;
  int d0 = dt8 * 256;
  int d  = d0 + tid;
  int t0g = b * L_SEQ + c * LC;

  ((f32x4*)Bs4)[tid] = ((const f32x4*)(Bbuf + (size_t)t0g * D_STATE))[tid];
  ((f32x4*)Cs4)[tid] = ((const f32x4*)(Cbuf + (size_t)t0g * D_STATE))[tid];

  float Ad[16], h[16];
  bool fast;
  load_Ad(A_log, d, Ad, fast);
  size_t base = ((size_t)(b * NC + c) * D_INNER + d) * 16;
  #pragma unroll
  for (int q = 0; q < 4; ++q)
    *(f32x4*)(h + q * 4) = *(const f32x4*)(hstart + base + q * 4);
  float Dv = Dw[d];

  for (int sub = 0; sub < 4; ++sub) {
    __syncthreads();
    #pragma unroll
    for (int rep = 0; rep < 2; ++rep) {
      int idx = rep * 256 + tid;
      int row = idx >> 5;
      int col = (idx & 31) * 8;
      size_t src = (size_t)(t0g + sub * 16 + row) * D_INNER + d0 + col;
      *(bf16x8*)(dts + row * 256 + col) = *(const bf16x8*)(dt + src);
      *(bf16x8*)(uts + row * 256 + col) = *(const bf16x8*)(uc_bf + src);
      *(bf16x8*)(zts + row * 256 + col) = *(const bf16x8*)(z_silu + src);
    }
    __syncthreads();
    for (int t = 0; t < 16; ++t) {
      float dtv = bf2f(dts[t * 256 + tid]);
      float uv  = bf2f(uts[t * 256 + tid]);
      float zv  = bf2f(zts[t * 256 + tid]);
      float su  = dtv * uv;
      float dec[16];
      compute_decay(fast, dtv, Ad, dec);
      const float* Bp = Bs4 + (sub * 16 + t) * 16;
      const float* Cp = Cs4 + (sub * 16 + t) * 16;
      float y = 0.0f;
      #pragma unroll
      for (int n = 0; n < 16; ++n) {
        h[n] = h[n] * dec[n] + su * Bp[n];
        y += h[n] * Cp[n];
      }
      y = (y + uv * Dv) * zv;
      y_bf[(size_t)(t0g + sub * 16 + t) * D_INNER + d] = f2bf(y);
    }
  }
}

// ---------------------------------------------------------------------------
// LayerNorm; fuses out_proj split-K=4 reduce (bf16 partials) + residual.
// ---------------------------------------------------------------------------
__global__ void ln_kernel(const bf16* __restrict__ partsA,
                          const bf16* __restrict__ partsB,
                          const bf16* __restrict__ x_bf,
                          const float* __restrict__ w,
                          const float* __restrict__ bia,
                          void* __restrict__ out,
                          const unsigned short* __restrict__ probe)
{
  int t = blockIdx.x;
  int tid = threadIdx.x;
  const bf16* p0 = partsA + (size_t)t * D_MODEL;
  const bf16* p1 = partsA + ((size_t)T_TOK + t) * D_MODEL;
  const bf16* p2 = partsB + (size_t)t * D_MODEL;
  const bf16* p3 = partsB + ((size_t)T_TOK + t) * D_MODEL;
  const bf16* xr = x_bf + (size_t)t * D_MODEL;
  float v[4];
  float s = 0.0f, q = 0.0f;
  #pragma unroll
  for (int k = 0; k < 4; ++k) {
    int col = tid + k * 256;
    v[k] = bf2f(p0[col]) + bf2f(p1[col]) + bf2f(p2[col]) + bf2f(p3[col]) + bf2f(xr[col]);
    s += v[k]; q += v[k] * v[k];
  }
  #pragma unroll
  for (int off = 32; off >= 1; off >>= 1) {
    s += __shfl_down(s, off);
    q += __shfl_down(q, off);
  }
  __shared__ float red[8];
  __shared__ float mv[2];
  int wave = tid >> 6, lane = tid & 63;
  if (lane == 0) { red[wave] = s; red[4 + wave] = q; }
  __syncthreads();
  if (tid == 0) {
    float S = red[0] + red[1] + red[2] + red[3];
    float Q = red[4] + red[5] + red[6] + red[7];
    float mu = S * (1.0f / D_MODEL);
    float var = Q * (1.0f / D_MODEL) - mu * mu;
    mv[0] = mu; mv[1] = rsqrtf(var + 1e-5f);
  }
  __syncthreads();
  float mu = mv[0], rs = mv[1];
  bool isf32 = probe_f32(probe);
  #pragma unroll
  for (int k = 0; k < 4; ++k) {
    int col = tid + k * 256;
    float r = (v[k] - mu) * rs * w[col] + bia[col];
    if (isf32) ((float*)out)[(size_t)t * D_MODEL + col] = r;
    else       ((bf16*) out)[(size_t)t * D_MODEL + col] = f2bf(r);
  }
}

// ---------------------------------------------------------------------------
extern "C" void kernel_launch(void* const* d_in, const int* in_sizes, int n_in,
                              void* d_out, int out_size, void* d_ws, size_t ws_size,
                              hipStream_t stream)
{
  const void* x        = d_in[0];
  const void* in_w     = d_in[1];
  const void* conv_w   = d_in[2];
  const void* conv_b   = d_in[3];
  const void* xproj_w  = d_in[4];
  const void* dtproj_w = d_in[5];
  const void* dtproj_b = d_in[6];
  const void* A_log    = d_in[7];
  const void* Dw       = d_in[8];
  const void* out_w    = d_in[9];
  const void* ln_w     = d_in[10];
  const void* ln_b     = d_in[11];
  const unsigned short* probe = (const unsigned short*)A_log;

  char* p = (char*)d_ws;
  auto alloc = [&](size_t bytes) { char* r = p; p += (bytes + 255) & ~255ull; return r; };
  bf16*  x_bf   = (bf16*) alloc((size_t)T_TOK * D_MODEL * 2);          // 8.4 MB
  bf16*  inw_bf = (bf16*) alloc((size_t)2 * D_INNER * D_MODEL * 2);    // 8.4 MB
  bf16*  xpw_bf = (bf16*) alloc((size_t)NXP * D_INNER * 2);            // 0.4 MB
  bf16*  dtw_bf = (bf16*) alloc((size_t)D_INNER * DT_RANK * 2);        // 0.26 MB
  bf16*  outw_bf= (bf16*) alloc((size_t)D_MODEL * D_INNER * 2);        // 4.2 MB
  float* params = (float*)alloc((size_t)P_TOT * 4);                    // 0.2 MB
  bf16*  u_pre  = (bf16*) alloc((size_t)T_TOK * D_INNER * 2);          // 16.8 MB (then xparts, then y_bf)
  bf16*  z_silu = (bf16*) alloc((size_t)T_TOK * D_INNER * 2);          // 16.8 MB (then outproj partials z=0,1)
  bf16*  uc_bf  = (bf16*) alloc((size_t)T_TOK * D_INNER * 2);          // 16.8 MB
  bf16*  dtlr   = (bf16*) alloc((size_t)T_TOK * DT_RANK * 2);          // 0.5 MB (unused, kept for layout)
  float* Bbuf   = (float*)alloc((size_t)T_TOK * D_STATE * 4);          // 0.26 MB
  float* Cbuf   = (float*)alloc((size_t)T_TOK * D_STATE * 4);          // 0.26 MB
  bf16*  dtb    = (bf16*) alloc((size_t)T_TOK * D_INNER * 2);          // 16.8 MB (dt; then outproj partials z=2,3)
  float* hend   = (float*)alloc((size_t)B_SZ * NC * D_INNER * 16 * 4); // 8.4 MB
  float* sumdt  = (float*)alloc((size_t)B_SZ * NC * D_INNER * 4);      // 0.5 MB
  (void)dtlr;
  bf16*  y_bf   = u_pre;            // u_pre dead after conv; xparts dead after dtfuse
  float* xparts = (float*)u_pre;    // u_pre dead after conv; 12.6 MB <= 16.8 MB
  bf16*  opartsA = z_silu;          // z dead after pass3
  bf16*  opartsB = dtb;             // dt dead after pass3

  dim3 blk(256);
  dim3 blk512(512);
  // 0) normalize ALL inputs in one launch (dtype-agnostic, vectorized)
  cvt_all<<<5304, blk, 0, stream>>>(x, in_w, xproj_w, dtproj_w, out_w,
                                    conv_w, conv_b, dtproj_b, A_log, Dw, ln_w, ln_b,
                                    x_bf, inw_bf, xpw_bf, dtw_bf, outw_bf, params, probe);

  // 1) in_proj (BM=BN=256, BK=64, 2-slot ring, counted vmcnt, XCD swizzle)
  k_inproj<<<dim3(T_TOK / 256, (2 * D_INNER) / 256), blk512, 0, stream>>>(x_bf, inw_bf, u_pre, z_silu);
  // 2) causal depthwise conv + bias + silu -> uc_bf (x4 vectorized)
  conv_silu_kernel<<<(T_TOK * D_INNER) / 1024, blk, 0, stream>>>(u_pre, params + P_CONVW, params + P_CONVB, uc_bf);
  // 3) x_proj split-K (register staging) -> f32 partials (in dead u_pre)
  k_xproj<<<dim3(T_TOK / 128, 1, KSPLIT), blk, 0, stream>>>(uc_bf, xpw_bf, xparts);
  // 4) FUSED partial-reduce + dt_proj + softplus, 512 blocks (round-6 fix)
  k_dtfuse<<<dim3(16, 32), blk, 0, stream>>>(xparts, dtw_bf, params + P_DTB, Bbuf, Cbuf, dtb);
  // 5-7) chunked selective scan (pass2 parallel prefix)
  scan_pass1<<<B_SZ * NC * (D_INNER / 256), blk, 0, stream>>>(dtb, uc_bf, Bbuf, params + P_ALOG, hend, sumdt);
  scan_pass2<<<(B_SZ * D_INNER) / 2, blk, 0, stream>>>(hend, sumdt, params + P_ALOG);
  scan_pass3<<<B_SZ * NC * (D_INNER / 256), blk, 0, stream>>>(
      dtb, uc_bf, Bbuf, Cbuf, z_silu, hend, params + P_ALOG, params + P_DW, y_bf);
  // 8) out_proj split-K=4 (pipelined body, XCD swizzle) -> partials
  k_outproj<<<dim3(T_TOK / 256, D_MODEL / 256, 4), blk512, 0, stream>>>(y_bf, outw_bf, opartsA, opartsB);
  // 9) layernorm (fused 4-way bf16 split-K reduce + residual) -> d_out
  ln_kernel<<<T_TOK, blk, 0, stream>>>(opartsA, opartsB, x_bf, params + P_LNW, params + P_LNB, d_out, probe);
}

// Round 7
// 294.594 us; speedup vs baseline: 1.3890x; 1.0327x over previous
//
#include <hip/hip_runtime.h>
#include <hip/hip_bf16.h>
#include <math.h>

#define DEV static __device__ __forceinline__

typedef __hip_bfloat16 bf16;
typedef __attribute__((ext_vector_type(8))) short bf16x8;   // 8 bf16 = 4 VGPRs
typedef __attribute__((ext_vector_type(4))) short bf16x4;   // 4 bf16 = 2 VGPRs
typedef __attribute__((ext_vector_type(4))) float f32x4;

static constexpr int D_MODEL = 1024;
static constexpr int D_INNER = 2048;
static constexpr int D_STATE = 16;
static constexpr int DT_RANK = 64;
static constexpr int B_SZ   = 2;
static constexpr int L_SEQ  = 2048;
static constexpr int T_TOK  = B_SZ * L_SEQ;   // 4096 tokens
static constexpr int LC     = 64;             // scan chunk length
static constexpr int NC     = L_SEQ / LC;     // 32 chunks per sequence
static constexpr int NXP    = DT_RANK + 2 * D_STATE;   // 96
static constexpr int KSPLIT = 8;              // x_proj split-K factor

// params (f32) layout inside ws
static constexpr int P_CONVW = 0;        // [2048*4]
static constexpr int P_CONVB = 8192;     // [2048]
static constexpr int P_DTB   = 10240;    // [2048]
static constexpr int P_ALOG  = 12288;    // [2048*16]
static constexpr int P_DW    = 45056;    // [2048]
static constexpr int P_LNW   = 47104;    // [1024]
static constexpr int P_LNB   = 48128;    // [1024]
static constexpr int P_TOT   = 49152;

DEV float bf2f(bf16 x) { return __bfloat162float(x); }
DEV bf16  f2bf(float x) { return __float2bfloat16(x); }
DEV float sigmoidf_(float x) { return 1.0f / (1.0f + __expf(-x)); }
DEV float s2f(short s) { bf16 b; __builtin_memcpy(&b, &s, 2); return bf2f(b); }
DEV short f2s(float x) { bf16 b = f2bf(x); short s; __builtin_memcpy(&s, &b, 2); return s; }

DEV bool probe_f32(const unsigned short* probe) { return probe[1] == 0; }

DEV void async_copy16(const void* g, void* l) {
  // DMA 16 B/lane: LDS dest = wave-uniform base + lane*16 (m97-verified)
  __builtin_amdgcn_global_load_lds(
      (const __attribute__((address_space(1))) void*)g,
      (__attribute__((address_space(3))) void*)l, 16, 0, 0);
}

template <int N>
DEV void vm_wait() {
  if constexpr (N == 6) asm volatile("s_waitcnt vmcnt(6)" ::: "memory");
  else                  asm volatile("s_waitcnt vmcnt(0)" ::: "memory");
}

// ---------------------------------------------------------------------------
// fused input normalization: ALL 12 tensors in one launch (8 elems/thread)
// ---------------------------------------------------------------------------
__global__ void cvt_all(const void* s0, const void* s1, const void* s2,
                        const void* s3, const void* s4,
                        const void* s5, const void* s6, const void* s7,
                        const void* s8, const void* s9, const void* s10,
                        const void* s11,
                        bf16* d0, bf16* d1, bf16* d2, bf16* d3, bf16* d4,
                        float* params,
                        const unsigned short* __restrict__ probe)
{
  long i = (long)(blockIdx.x * 256 + threadIdx.x) * 8;
  const void* src; long off;
  bf16* dstb = nullptr; float* dstf = nullptr;
  if      (i <  4194304) { src = s0;  dstb = d0; off = i; }
  else if (i <  8388608) { src = s1;  dstb = d1; off = i - 4194304; }
  else if (i <  8585216) { src = s2;  dstb = d2; off = i - 8388608; }
  else if (i <  8716288) { src = s3;  dstb = d3; off = i - 8585216; }
  else if (i < 10813440) { src = s4;  dstb = d4; off = i - 8716288; }
  else if (i < 10821632) { src = s5;  dstf = params + P_CONVW; off = i - 10813440; }
  else if (i < 10823680) { src = s6;  dstf = params + P_CONVB; off = i - 10821632; }
  else if (i < 10825728) { src = s7;  dstf = params + P_DTB;   off = i - 10823680; }
  else if (i < 10858496) { src = s8;  dstf = params + P_ALOG;  off = i - 10825728; }
  else if (i < 10860544) { src = s9;  dstf = params + P_DW;    off = i - 10858496; }
  else if (i < 10861568) { src = s10; dstf = params + P_LNW;   off = i - 10860544; }
  else if (i < 10862592) { src = s11; dstf = params + P_LNB;   off = i - 10861568; }
  else return;
  bool isf32 = probe_f32(probe);
  float v[8];
  if (isf32) {
    float4 a = *(const float4*)((const float*)src + off);
    float4 b = *(const float4*)((const float*)src + off + 4);
    v[0]=a.x; v[1]=a.y; v[2]=a.z; v[3]=a.w;
    v[4]=b.x; v[5]=b.y; v[6]=b.z; v[7]=b.w;
  } else {
    bf16x8 t = *(const bf16x8*)((const bf16*)src + off);
    #pragma unroll
    for (int k = 0; k < 8; ++k) { short sk = t[k]; v[k] = s2f(sk); }
  }
  if (dstb) {
    bf16x8 o;
    #pragma unroll
    for (int k = 0; k < 8; ++k) o[k] = f2s(v[k]);
    *(bf16x8*)(dstb + off) = o;
  } else {
    f32x4 a = {v[0], v[1], v[2], v[3]};
    f32x4 b = {v[4], v[5], v[6], v[7]};
    *(f32x4*)(dstf + off)     = a;
    *(f32x4*)(dstf + off + 4) = b;
  }
}

// ---------------------------------------------------------------------------
// 8-wave counted-vmcnt pipelined GEMM (R2 config, measured best: 46.9us,
// 0 bank conflicts): BM=256, BN=128, BK=64, waves own 64x64 sub-tiles.
// LDS 3-slot ring (144 KiB), prefetch distance 2, vmcnt(6) per tile.
// 128B LDS rows + 8-chunk XOR swizzle.
// MODE 0: in_proj + FUSED conv+silu epilogue:
//   u-half blocks (bn<2048): acc -> LDS u-tile + 3-row halo (f32 dot) ->
//   causal conv W=4 + bias + silu -> o0=uc_bf. u_pre NEVER goes to HBM.
//   z-half blocks: silu -> o1=z_silu.
// MODE 3: out_proj split-K=2 -> o0 = bf16 partials [kz][t][1024]
// ---------------------------------------------------------------------------
static constexpr int SLOT = 48 * 1024;
static constexpr int BOFF = 32 * 1024;

DEV void stage_A(const bf16* __restrict__ A, int ld, int bm, int k0,
                 char* slot, int tid) {
  #pragma unroll
  for (int j = 0; j < 4; ++j) {
    int p   = j * 8192 + tid * 16;           // linear LDS dest byte
    int row = p >> 7;                        // 0..255 (128B rows)
    int ck  = ((p >> 4) & 7) ^ (row & 7);    // inverse-swizzled 16B chunk
    async_copy16(A + (size_t)(bm + row) * ld + k0 + ck * 8,
                 slot + j * 8192 + (tid >> 6) * 1024);
  }
}

DEV void stage_B(const bf16* __restrict__ B, int ld, int bn, int k0,
                 char* slot, int tid) {
  #pragma unroll
  for (int j = 0; j < 2; ++j) {
    int p   = j * 8192 + tid * 16;
    int row = p >> 7;                        // 0..127
    int ck  = ((p >> 4) & 7) ^ (row & 7);
    async_copy16(B + (size_t)(bn + row) * ld + k0 + ck * 8,
                 slot + BOFF + j * 8192 + (tid >> 6) * 1024);
  }
}

template <int MODE>
DEV void gemm_pipe(const bf16* __restrict__ A, const bf16* __restrict__ B,
                   int M, int K, int ld,
                   void* __restrict__ o0, void* __restrict__ o1,
                   const float* __restrict__ cw, const float* __restrict__ cb)
{
  __shared__ __align__(16) char ring[3 * SLOT];   // 144 KiB
  const bf16* Aorig = A;
  const bf16* Borig = B;
  if (MODE == 3) {
    A += (size_t)blockIdx.z * K;
    B += (size_t)blockIdx.z * K;
  }
  const int tid  = threadIdx.x;
  const int wave = tid >> 6;
  const int lane = tid & 63;
  const int bm = blockIdx.x * 256;
  const int bn = blockIdx.y * 128;
  const int wm = (wave >> 1) * 64;       // 0..192: A row group
  const int wn = (wave & 1) * 64;        // 0/64:   B row group
  const int fr = lane & 15;
  const int fq = lane >> 4;              // 0..3
  const int NT = K / 64;

  f32x4 acc[4][4];
  #pragma unroll
  for (int i = 0; i < 4; ++i)
    #pragma unroll
    for (int j = 0; j < 4; ++j)
      #pragma unroll
      for (int r = 0; r < 4; ++r) acc[i][j][r] = 0.0f;

  // prologue: stage tiles 0 and 1 (12 loads/thread in flight)
  stage_A(A, ld, bm, 0,  ring,        tid);
  stage_B(B, ld, bn, 0,  ring,        tid);
  stage_A(A, ld, bm, 64, ring + SLOT, tid);
  stage_B(B, ld, bn, 64, ring + SLOT, tid);

  int scur = 0;
  #pragma unroll 1
  for (int tk = 0; tk < NT; ++tk) {
    if (tk < NT - 1) vm_wait<6>();
    else             vm_wait<0>();
    __builtin_amdgcn_sched_barrier(0);
    __builtin_amdgcn_s_barrier();
    __builtin_amdgcn_sched_barrier(0);

    const char* sa = ring + scur * SLOT;
    int snxt = scur + 2; if (snxt >= 3) snxt -= 3;
    char* sn = ring + snxt * SLOT;

    // ---- phase 0: A frags (8 reads) + B frags ni=0..1 (4 reads) ----
    bf16x8 af[4][2], bg[2][2];
    #pragma unroll
    for (int mi = 0; mi < 4; ++mi)
      #pragma unroll
      for (int kk = 0; kk < 2; ++kk) {
        int row = wm + mi * 16 + fr;
        af[mi][kk] = *(const bf16x8*)(sa + row * 128 + (((kk * 4 + fq) ^ (fr & 7)) * 16));
      }
    #pragma unroll
    for (int ni = 0; ni < 2; ++ni)
      #pragma unroll
      for (int kk = 0; kk < 2; ++kk) {
        int row = wn + ni * 16 + fr;
        bg[ni][kk] = *(const bf16x8*)(sa + BOFF + row * 128 + (((kk * 4 + fq) ^ (fr & 7)) * 16));
      }
    __builtin_amdgcn_sched_barrier(0);
    if (tk + 2 < NT) stage_A(A, ld, bm, (tk + 2) * 64, sn, tid);
    __builtin_amdgcn_sched_barrier(0);
    asm volatile("s_waitcnt lgkmcnt(0)" ::: "memory");
    __builtin_amdgcn_sched_barrier(0);
    __builtin_amdgcn_s_setprio(1);
    #pragma unroll
    for (int kk = 0; kk < 2; ++kk)
      #pragma unroll
      for (int mi = 0; mi < 4; ++mi)
        #pragma unroll
        for (int ni = 0; ni < 2; ++ni)
          acc[mi][ni] = __builtin_amdgcn_mfma_f32_16x16x32_bf16(af[mi][kk], bg[ni][kk], acc[mi][ni], 0, 0, 0);
    __builtin_amdgcn_s_setprio(0);
    __builtin_amdgcn_sched_barrier(0);

    // ---- phase 1: B frags ni=2..3 (4 reads), A frags reused ----
    bf16x8 bh[2][2];
    #pragma unroll
    for (int ni = 0; ni < 2; ++ni)
      #pragma unroll
      for (int kk = 0; kk < 2; ++kk) {
        int row = wn + (ni + 2) * 16 + fr;
        bh[ni][kk] = *(const bf16x8*)(sa + BOFF + row * 128 + (((kk * 4 + fq) ^ (fr & 7)) * 16));
      }
    __builtin_amdgcn_sched_barrier(0);
    if (tk + 2 < NT) stage_B(B, ld, bn, (tk + 2) * 64, sn, tid);
    __builtin_amdgcn_sched_barrier(0);
    asm volatile("s_waitcnt lgkmcnt(0)" ::: "memory");
    __builtin_amdgcn_sched_barrier(0);
    __builtin_amdgcn_s_setprio(1);
    #pragma unroll
    for (int kk = 0; kk < 2; ++kk)
      #pragma unroll
      for (int mi = 0; mi < 4; ++mi)
        #pragma unroll
        for (int ni = 0; ni < 2; ++ni)
          acc[mi][ni + 2] = __builtin_amdgcn_mfma_f32_16x16x32_bf16(af[mi][kk], bh[ni][kk], acc[mi][ni + 2], 0, 0, 0);
    __builtin_amdgcn_s_setprio(0);
    __builtin_amdgcn_sched_barrier(0);

    scur = (scur + 1 == 3) ? 0 : scur + 1;
  }

  const int er = (lane >> 4) * 4;     // C/D: row = er + reg, col = lane&15
  const int ec = lane & 15;

  if (MODE == 3) {
    #pragma unroll
    for (int mi = 0; mi < 4; ++mi)
      #pragma unroll
      for (int ni = 0; ni < 4; ++ni)
        #pragma unroll
        for (int r = 0; r < 4; ++r) {
          int row = bm + wm + mi * 16 + er + r;
          int col = bn + wn + ni * 16 + ec;
          ((bf16*)o0)[((size_t)blockIdx.z * M + row) * D_MODEL + col] = f2bf(acc[mi][ni][r]);
        }
    return;
  }

  // ================= MODE 0 fused epilogue =================
  if (bn >= D_INNER) {
    // z-half: silu -> z_silu
    #pragma unroll
    for (int mi = 0; mi < 4; ++mi)
      #pragma unroll
      for (int ni = 0; ni < 4; ++ni)
        #pragma unroll
        for (int r = 0; r < 4; ++r) {
          int row = bm + wm + mi * 16 + er + r;
          int col = bn + wn + ni * 16 + ec - D_INNER;
          float v = acc[mi][ni][r];
          ((bf16*)o1)[(size_t)row * D_INNER + col] = f2bf(v * sigmoidf_(v));
        }
    return;
  }

  // u-half: fused causal conv (W=4) + bias + silu.
  // LDS layout (reusing ring): u tile [259][136] bf16 (rows 0-2 = halo
  // tokens bm-3..bm-1, rows 3-258 = tokens bm..bm+255; 136-stride breaks
  // the 256B-row bank alias), then cws[128][4] f32, cbs[128] f32.
  __syncthreads();                        // all ring reads done
  bf16*  uT  = (bf16*)ring;               // 259*136*2 = 70448 B
  float* cws = (float*)(ring + 70656);
  float* cbs = (float*)(ring + 72704);

  #pragma unroll
  for (int mi = 0; mi < 4; ++mi)
    #pragma unroll
    for (int ni = 0; ni < 4; ++ni)
      #pragma unroll
      for (int r = 0; r < 4; ++r)
        uT[(size_t)(wm + mi * 16 + er + r + 3) * 136 + wn + ni * 16 + ec] = f2bf(acc[mi][ni][r]);

  if (tid < 128) {
    *(f32x4*)(cws + tid * 4) = *(const f32x4*)(cw + (size_t)(bn + tid) * 4);
    cbs[tid] = cb[bn + tid];
  }

  // halo: recompute u_pre rows bm-3..bm-1 for this block's 128 cols via
  // f32 dot (skipped at sequence starts, where the causal guard masks them)
  if ((bm & (L_SEQ - 1)) != 0 && tid < 384) {
    int j = tid >> 7;                     // 0..2
    int c = tid & 127;
    const bf16* xr = Aorig + (size_t)(bm - 3 + j) * ld;
    const bf16* wr = Borig + (size_t)(bn + c) * ld;
    float s = 0.0f;
    for (int k8 = 0; k8 < 1024; k8 += 8) {
      bf16x8 xa = *(const bf16x8*)(xr + k8);
      bf16x8 wb = *(const bf16x8*)(wr + k8);
      #pragma unroll
      for (int q = 0; q < 8; ++q) { short a = xa[q], b = wb[q]; s += s2f(a) * s2f(b); }
    }
    uT[(size_t)j * 136 + c] = f2bf(s);
  }
  __syncthreads();

  // conv + silu -> uc. Thread t: col-group cg = t&15 (8 cols), rows
  // (t>>4) + j*32 (8 rows). Per-wave store = 4 rows x 128 cols coalesced.
  const int cg = tid & 15;
  float cwr[4][8], cbr[8];
  #pragma unroll
  for (int i = 0; i < 8; ++i) {
    f32x4 w4 = *(const f32x4*)(cws + (cg * 8 + i) * 4);
    cwr[0][i] = w4[0]; cwr[1][i] = w4[1]; cwr[2][i] = w4[2]; cwr[3][i] = w4[3];
    cbr[i] = cbs[cg * 8 + i];
  }
  const int lbase = bm & (L_SEQ - 1);
  #pragma unroll
  for (int j = 0; j < 8; ++j) {
    int row = (tid >> 4) + j * 32;        // 0..255
    float a8[8];
    #pragma unroll
    for (int i = 0; i < 8; ++i) a8[i] = cbr[i];
    #pragma unroll
    for (int w = 0; w < 4; ++w) {
      if (lbase + row - 3 + w >= 0) {     // causal guard (sequence start)
        bf16x8 u8 = *(const bf16x8*)(uT + (size_t)(row + w) * 136 + cg * 8);
        #pragma unroll
        for (int i = 0; i < 8; ++i) { short uu = u8[i]; a8[i] += s2f(uu) * cwr[w][i]; }
      }
    }
    bf16x8 o;
    #pragma unroll
    for (int i = 0; i < 8; ++i) o[i] = f2s(a8[i] * sigmoidf_(a8[i]));
    *(bf16x8*)((bf16*)o0 + (size_t)(bm + row) * D_INNER + bn + cg * 8) = o;
  }
}

// ---------------------------------------------------------------------------
// BK=32 register-staged GEMM body (x_proj split-K -> f32 partials)
// ---------------------------------------------------------------------------
__global__ void __launch_bounds__(256) k_xproj(const bf16* __restrict__ A,
                                               const bf16* __restrict__ B,
                                               float* __restrict__ o0)
{
  __shared__ __align__(16) bf16 As[128 * 32];
  __shared__ __align__(16) bf16 Bs[128 * 32];
  const int M = T_TOK, N = NXP, K = D_INNER / KSPLIT, ld = D_INNER;
  A += (size_t)blockIdx.z * K;
  B += (size_t)blockIdx.z * K;
  const int tid  = threadIdx.x;
  const int wave = tid >> 6;
  const int lane = tid & 63;
  const int bm = blockIdx.x * 128;
  const int bn = 0;
  const int wm = (wave >> 1) * 64;
  const int wn = (wave & 1) * 64;

  f32x4 acc[4][4];
  #pragma unroll
  for (int i = 0; i < 4; ++i)
    #pragma unroll
    for (int j = 0; j < 4; ++j)
      #pragma unroll
      for (int r = 0; r < 4; ++r) acc[i][j][r] = 0.0f;

  const int ar0 = tid >> 2;
  const int ar1 = ar0 + 64;
  const int ac  = (tid & 3) * 8;
  const int fr = lane & 15;
  const int fk = (lane >> 4) * 8;

  for (int k0 = 0; k0 < K; k0 += 32) {
    bf16x8 a0 = *(const bf16x8*)(A + (size_t)(bm + ar0) * ld + k0 + ac);
    bf16x8 a1 = *(const bf16x8*)(A + (size_t)(bm + ar1) * ld + k0 + ac);
    int r0 = bn + ar0; if (r0 > N - 1) r0 = N - 1;
    int r1 = bn + ar1; if (r1 > N - 1) r1 = N - 1;
    bf16x8 b0 = *(const bf16x8*)(B + (size_t)r0 * ld + k0 + ac);
    bf16x8 b1 = *(const bf16x8*)(B + (size_t)r1 * ld + k0 + ac);
    __syncthreads();
    *(bf16x8*)(As + ar0 * 32 + ac) = a0;
    *(bf16x8*)(As + ar1 * 32 + ac) = a1;
    *(bf16x8*)(Bs + ar0 * 32 + ac) = b0;
    *(bf16x8*)(Bs + ar1 * 32 + ac) = b1;
    __syncthreads();

    bf16x8 af[4], bg[4];
    #pragma unroll
    for (int mi = 0; mi < 4; ++mi)
      af[mi] = *(const bf16x8*)(As + (wm + mi * 16 + fr) * 32 + fk);
    #pragma unroll
    for (int ni = 0; ni < 4; ++ni)
      bg[ni] = *(const bf16x8*)(Bs + (wn + ni * 16 + fr) * 32 + fk);
    #pragma unroll
    for (int mi = 0; mi < 4; ++mi)
      #pragma unroll
      for (int ni = 0; ni < 4; ++ni)
        acc[mi][ni] = __builtin_amdgcn_mfma_f32_16x16x32_bf16(af[mi], bg[ni], acc[mi][ni], 0, 0, 0);
  }

  const int er = (lane >> 4) * 4;
  const int ec = lane & 15;
  #pragma unroll
  for (int mi = 0; mi < 4; ++mi)
    #pragma unroll
    for (int ni = 0; ni < 4; ++ni)
      #pragma unroll
      for (int r = 0; r < 4; ++r) {
        int row = bm + wm + mi * 16 + er + r;
        int col = bn + wn + ni * 16 + ec;
        if (col >= N) continue;
        o0[((size_t)blockIdx.z * M + row) * N + col] = acc[mi][ni][r];
      }
}

// distinct names so rocprof disambiguates the stages
__global__ void __launch_bounds__(512) k_inproj(const bf16* A, const bf16* B,
    void* o0, void* o1, const float* cw, const float* cb) {
  gemm_pipe<0>(A, B, T_TOK, D_MODEL, D_MODEL, o0, o1, cw, cb);
}
__global__ void __launch_bounds__(512) k_outproj(const bf16* A, const bf16* B,
    void* o0) {
  gemm_pipe<3>(A, B, T_TOK, D_INNER / 2, D_INNER, o0, nullptr, nullptr, nullptr);
}

// ---------------------------------------------------------------------------
// FUSED x_proj split-K reduce + dt_proj GEMM + softplus (512 blocks).
// Each block redundantly reduces its 128x64 dtlr tile (XCD-chunked swizzle
// keeps a token-slab's 16 col-blocks on one XCD -> L2-hit re-reads) and
// computes one 128x128 K=64 MFMA GEMM + softplus. col-block 0 writes B/C.
// ---------------------------------------------------------------------------
__global__ __launch_bounds__(256) void k_dtfuse(
    const float* __restrict__ partials,   // [8][T_TOK][96]
    const bf16*  __restrict__ dtw,        // [2048][64] bf16
    const float* __restrict__ dtbias,     // [2048] f32
    float* __restrict__ Bbuf, float* __restrict__ Cbuf,
    bf16* __restrict__ dtb)
{
  __shared__ __align__(16) bf16 Al[128 * 72];   // 18 KB (dtlr tile, pad 72)
  __shared__ __align__(16) bf16 Bl[128 * 72];   // 18 KB (dtw tile)
  const int tid = threadIdx.x;
  unsigned lin = blockIdx.x + gridDim.x * blockIdx.y;
  unsigned nid = (lin & 7) * 64 + (lin >> 3);   // nwg=512, cpx=64
  const int cblk = nid & 15;
  const int tblk = nid >> 4;
  const int r0 = tblk * 128;
  const int c0 = cblk * 128;

  #pragma unroll
  for (int it = 0; it < 8; ++it) {
    int idx = it * 256 + tid;            // 128 rows x 16 f32x4 groups
    int row = idx >> 4;
    int g   = idx & 15;
    f32x4 s = {0.0f, 0.0f, 0.0f, 0.0f};
    #pragma unroll
    for (int kz = 0; kz < KSPLIT; ++kz)
      s += *(const f32x4*)(partials + ((size_t)kz * T_TOK + r0 + row) * NXP + g * 4);
    bf16x4 o;
    #pragma unroll
    for (int k = 0; k < 4; ++k) o[k] = f2s(s[k]);
    *(bf16x4*)(Al + row * 72 + g * 4) = o;
  }
  if (cblk == 0) {
    #pragma unroll
    for (int it = 0; it < 4; ++it) {
      int idx = it * 256 + tid;          // 128 rows x 8 groups
      int row = idx >> 3;
      int g   = 16 + (idx & 7);
      f32x4 s = {0.0f, 0.0f, 0.0f, 0.0f};
      #pragma unroll
      for (int kz = 0; kz < KSPLIT; ++kz)
        s += *(const f32x4*)(partials + ((size_t)kz * T_TOK + r0 + row) * NXP + g * 4);
      if (g < 20) *(f32x4*)(Bbuf + (size_t)(r0 + row) * D_STATE + (g - 16) * 4) = s;
      else        *(f32x4*)(Cbuf + (size_t)(r0 + row) * D_STATE + (g - 20) * 4) = s;
    }
  }
  #pragma unroll
  for (int it = 0; it < 4; ++it) {
    int idx = it * 256 + tid;            // 1024 bf16x8 groups
    int row = idx >> 3;
    int cv  = (idx & 7) * 8;
    *(bf16x8*)(Bl + row * 72 + cv) = *(const bf16x8*)(dtw + (size_t)(c0 + row) * 64 + cv);
  }
  __syncthreads();

  const int wave = tid >> 6;
  const int lane = tid & 63;
  const int wm = (wave >> 1) * 64;
  const int wn = (wave & 1) * 64;
  const int fr = lane & 15;
  const int fk = (lane >> 4) * 8;
  const int er = (lane >> 4) * 4;
  const int ec = lane & 15;

  f32x4 acc[4][4];
  #pragma unroll
  for (int i = 0; i < 4; ++i)
    #pragma unroll
    for (int j = 0; j < 4; ++j)
      #pragma unroll
      for (int r = 0; r < 4; ++r) acc[i][j][r] = 0.0f;

  #pragma unroll
  for (int k0 = 0; k0 < 64; k0 += 32) {
    bf16x8 af[4], bg[4];
    #pragma unroll
    for (int mi = 0; mi < 4; ++mi)
      af[mi] = *(const bf16x8*)(Al + (wm + mi * 16 + fr) * 72 + k0 + fk);
    #pragma unroll
    for (int ni = 0; ni < 4; ++ni)
      bg[ni] = *(const bf16x8*)(Bl + (wn + ni * 16 + fr) * 72 + k0 + fk);
    #pragma unroll
    for (int mi = 0; mi < 4; ++mi)
      #pragma unroll
      for (int ni = 0; ni < 4; ++ni)
        acc[mi][ni] = __builtin_amdgcn_mfma_f32_16x16x32_bf16(af[mi], bg[ni], acc[mi][ni], 0, 0, 0);
  }

  #pragma unroll
  for (int mi = 0; mi < 4; ++mi)
    #pragma unroll
    for (int ni = 0; ni < 4; ++ni)
      #pragma unroll
      for (int r = 0; r < 4; ++r) {
        int orow = r0 + wm + mi * 16 + er + r;
        int ocol = c0 + wn + ni * 16 + ec;
        float v = acc[mi][ni][r] + dtbias[ocol];
        float sp = (v > 15.0f) ? v : __logf(1.0f + __expf(v));
        dtb[(size_t)orow * D_INNER + ocol] = f2bf(sp);
      }
}

// ---------------------------------------------------------------------------
// helpers for the scan kernels
// ---------------------------------------------------------------------------
DEV void load_Ad(const float* A_log, int d, float* Ad, bool& fast) {
  fast = true;
  #pragma unroll
  for (int n = 0; n < 16; ++n) {
    Ad[n] = -__expf(A_log[d * 16 + n]);
    fast = fast && (fabsf(Ad[n] + (float)(n + 1)) < 1e-3f * (n + 1));
  }
}
DEV void compute_decay(bool fast, float dtv, const float* Ad, float* dec) {
  if (fast) {                       // A_n = -(n+1): decay_n = exp(-dt)^(n+1)
    float e1 = __expf(-dtv);
    float en = e1;
    #pragma unroll
    for (int n = 0; n < 16; ++n) { dec[n] = en; en *= e1; }
  } else {
    #pragma unroll
    for (int n = 0; n < 16; ++n) dec[n] = __expf(Ad[n] * dtv);
  }
}

// ---------------------------------------------------------------------------
// Scan pass 1: per-(b,chunk,d) local scan from h=0 -> chunk-end state + sum(dt)
// ---------------------------------------------------------------------------
__global__ __launch_bounds__(256) void scan_pass1(
    const bf16* __restrict__ dt, const bf16* __restrict__ uc_bf,
    const float* __restrict__ Bbuf, const float* __restrict__ A_log,
    float* __restrict__ hend, float* __restrict__ sumdt)
{
  __shared__ float Bs4[LC * D_STATE];         // 4 KB
  __shared__ bf16 dts[16 * 256];              // 8 KB
  __shared__ bf16 uts[16 * 256];              // 8 KB
  int bid = blockIdx.x;
  int tid = threadIdx.x;
  int dt8 = bid & 7;
  int c = (bid >> 3) & (NC - 1);
  int b = bid >> 8;
  int d0 = dt8 * 256;
  int d  = d0 + tid;
  int t0g = b * L_SEQ + c * LC;

  ((f32x4*)Bs4)[tid] = ((const f32x4*)(Bbuf + (size_t)t0g * D_STATE))[tid];

  float Ad[16], h[16];
  bool fast;
  load_Ad(A_log, d, Ad, fast);
  #pragma unroll
  for (int n = 0; n < 16; ++n) h[n] = 0.0f;
  float sdt = 0.0f;

  for (int sub = 0; sub < 4; ++sub) {
    __syncthreads();
    #pragma unroll
    for (int rep = 0; rep < 2; ++rep) {
      int idx = rep * 256 + tid;
      int row = idx >> 5;
      int col = (idx & 31) * 8;
      size_t src = (size_t)(t0g + sub * 16 + row) * D_INNER + d0 + col;
      *(bf16x8*)(dts + row * 256 + col) = *(const bf16x8*)(dt + src);
      *(bf16x8*)(uts + row * 256 + col) = *(const bf16x8*)(uc_bf + src);
    }
    __syncthreads();
    for (int t = 0; t < 16; ++t) {
      float dtv = bf2f(dts[t * 256 + tid]);
      float uv  = bf2f(uts[t * 256 + tid]);
      float su  = dtv * uv;
      sdt += dtv;
      float dec[16];
      compute_decay(fast, dtv, Ad, dec);
      const float* Bp = Bs4 + (sub * 16 + t) * 16;
      #pragma unroll
      for (int n = 0; n < 16; ++n)
        h[n] = h[n] * dec[n] + su * Bp[n];
    }
  }
  size_t base = ((size_t)(b * NC + c) * D_INNER + d) * 16;
  #pragma unroll
  for (int q = 0; q < 4; ++q)
    *(f32x4*)(hend + base + q * 4) = *(f32x4*)(h + q * 4);
  sumdt[(size_t)(b * NC + c) * D_INNER + d] = sdt;
}

// ---------------------------------------------------------------------------
// Scan pass 2: PARALLEL affine prefix scan over chunks.
// ---------------------------------------------------------------------------
__global__ __launch_bounds__(256) void scan_pass2(
    float* __restrict__ hend, const float* __restrict__ sumdt,
    const float* __restrict__ A_log)
{
  __shared__ float Ms[4][64];
  __shared__ float Es[4][64];
  int bid = blockIdx.x;                // 1024 blocks
  int tid = threadIdx.x;
  int cg   = tid >> 6;                 // 0..3
  int lane = tid & 63;
  int dloc = lane >> 4;                // 0..3
  int n    = lane & 15;
  int b     = bid >> 9;
  int d     = (bid & 511) * 4 + dloc;

  float a = -__expf(A_log[d * 16 + n]);

  float Ml[8], El[8];
  float M = 1.0f, E = 0.0f;
  #pragma unroll
  for (int j = 0; j < 8; ++j) {
    int c = cg * 8 + j;
    size_t sbase = (size_t)(b * NC + c) * D_INNER + d;
    float m = __expf(a * sumdt[sbase]);
    float e = hend[sbase * 16 + n];
    Ml[j] = M; El[j] = E;              // exclusive local prefix
    M = m * M;
    E = m * E + e;
  }
  Ms[cg][lane] = M;
  Es[cg][lane] = E;
  __syncthreads();
  float Ep = 0.0f;                     // exclusive group prefix (groups < cg)
  for (int g = 0; g < cg; ++g) {
    float Mg = Ms[g][lane], Eg = Es[g][lane];
    Ep = Mg * Ep + Eg;
  }
  #pragma unroll
  for (int j = 0; j < 8; ++j) {
    int c = cg * 8 + j;
    size_t sbase = (size_t)(b * NC + c) * D_INNER + d;
    hend[sbase * 16 + n] = Ml[j] * Ep + El[j];   // h at chunk start
  }
}

// ---------------------------------------------------------------------------
// Scan pass 3: re-scan with correct h0; y = (dot(h,C) + u*D) * silu(z) -> bf16
// ---------------------------------------------------------------------------
__global__ __launch_bounds__(256) void scan_pass3(
    const bf16* __restrict__ dt, const bf16* __restrict__ uc_bf,
    const float* __restrict__ Bbuf, const float* __restrict__ Cbuf,
    const bf16* __restrict__ z_silu, const float* __restrict__ hstart,
    const float* __restrict__ A_log, const float* __restrict__ Dw,
    bf16* __restrict__ y_bf)
{
  __shared__ float Bs4[LC * D_STATE];         // 4 KB
  __shared__ float Cs4[LC * D_STATE];         // 4 KB
  __shared__ bf16 dts[16 * 256];              // 8 KB
  __shared__ bf16 uts[16 * 256];              // 8 KB
  __shared__ bf16 zts[16 * 256];              // 8 KB
  int bid = blockIdx.x;
  int tid = threadIdx.x;
  int dt8 = bid & 7;
  int c = (bid >> 3) & (NC - 1);
  int b = bid >> 8;
  int d0 = dt8 * 256;
  int d  = d0 + tid;
  int t0g = b * L_SEQ + c * LC;

  ((f32x4*)Bs4)[tid] = ((const f32x4*)(Bbuf + (size_t)t0g * D_STATE))[tid];
  ((f32x4*)Cs4)[tid] = ((const f32x4*)(Cbuf + (size_t)t0g * D_STATE))[tid];

  float Ad[16], h[16];
  bool fast;
  load_Ad(A_log, d, Ad, fast);
  size_t base = ((size_t)(b * NC + c) * D_INNER + d) * 16;
  #pragma unroll
  for (int q = 0; q < 4; ++q)
    *(f32x4*)(h + q * 4) = *(const f32x4*)(hstart + base + q * 4);
  float Dv = Dw[d];

  for (int sub = 0; sub < 4; ++sub) {
    __syncthreads();
    #pragma unroll
    for (int rep = 0; rep < 2; ++rep) {
      int idx = rep * 256 + tid;
      int row = idx >> 5;
      int col = (idx & 31) * 8;
      size_t src = (size_t)(t0g + sub * 16 + row) * D_INNER + d0 + col;
      *(bf16x8*)(dts + row * 256 + col) = *(const bf16x8*)(dt + src);
      *(bf16x8*)(uts + row * 256 + col) = *(const bf16x8*)(uc_bf + src);
      *(bf16x8*)(zts + row * 256 + col) = *(const bf16x8*)(z_silu + src);
    }
    __syncthreads();
    for (int t = 0; t < 16; ++t) {
      float dtv = bf2f(dts[t * 256 + tid]);
      float uv  = bf2f(uts[t * 256 + tid]);
      float zv  = bf2f(zts[t * 256 + tid]);
      float su  = dtv * uv;
      float dec[16];
      compute_decay(fast, dtv, Ad, dec);
      const float* Bp = Bs4 + (sub * 16 + t) * 16;
      const float* Cp = Cs4 + (sub * 16 + t) * 16;
      float y = 0.0f;
      #pragma unroll
      for (int n = 0; n < 16; ++n) {
        h[n] = h[n] * dec[n] + su * Bp[n];
        y += h[n] * Cp[n];
      }
      y = (y + uv * Dv) * zv;
      y_bf[(size_t)(t0g + sub * 16 + t) * D_INNER + d] = f2bf(y);
    }
  }
}

// ---------------------------------------------------------------------------
// LayerNorm; fuses out_proj split-K=2 reduce (bf16 partials) + residual.
// ---------------------------------------------------------------------------
__global__ void ln_kernel(const bf16* __restrict__ parts,
                          const bf16* __restrict__ x_bf,
                          const float* __restrict__ w,
                          const float* __restrict__ bia,
                          void* __restrict__ out,
                          const unsigned short* __restrict__ probe)
{
  int t = blockIdx.x;
  int tid = threadIdx.x;
  const bf16* p0 = parts + (size_t)t * D_MODEL;
  const bf16* p1 = parts + ((size_t)T_TOK + t) * D_MODEL;
  const bf16* xr = x_bf + (size_t)t * D_MODEL;
  float v[4];
  float s = 0.0f, q = 0.0f;
  #pragma unroll
  for (int k = 0; k < 4; ++k) {
    int col = tid + k * 256;
    v[k] = bf2f(p0[col]) + bf2f(p1[col]) + bf2f(xr[col]);
    s += v[k]; q += v[k] * v[k];
  }
  #pragma unroll
  for (int off = 32; off >= 1; off >>= 1) {
    s += __shfl_down(s, off);
    q += __shfl_down(q, off);
  }
  __shared__ float red[8];
  __shared__ float mv[2];
  int wave = tid >> 6, lane = tid & 63;
  if (lane == 0) { red[wave] = s; red[4 + wave] = q; }
  __syncthreads();
  if (tid == 0) {
    float S = red[0] + red[1] + red[2] + red[3];
    float Q = red[4] + red[5] + red[6] + red[7];
    float mu = S * (1.0f / D_MODEL);
    float var = Q * (1.0f / D_MODEL) - mu * mu;
    mv[0] = mu; mv[1] = rsqrtf(var + 1e-5f);
  }
  __syncthreads();
  float mu = mv[0], rs = mv[1];
  bool isf32 = probe_f32(probe);
  #pragma unroll
  for (int k = 0; k < 4; ++k) {
    int col = tid + k * 256;
    float r = (v[k] - mu) * rs * w[col] + bia[col];
    if (isf32) ((float*)out)[(size_t)t * D_MODEL + col] = r;
    else       ((bf16*) out)[(size_t)t * D_MODEL + col] = f2bf(r);
  }
}

// ---------------------------------------------------------------------------
extern "C" void kernel_launch(void* const* d_in, const int* in_sizes, int n_in,
                              void* d_out, int out_size, void* d_ws, size_t ws_size,
                              hipStream_t stream)
{
  const void* x        = d_in[0];
  const void* in_w     = d_in[1];
  const void* conv_w   = d_in[2];
  const void* conv_b   = d_in[3];
  const void* xproj_w  = d_in[4];
  const void* dtproj_w = d_in[5];
  const void* dtproj_b = d_in[6];
  const void* A_log    = d_in[7];
  const void* Dw       = d_in[8];
  const void* out_w    = d_in[9];
  const void* ln_w     = d_in[10];
  const void* ln_b     = d_in[11];
  const unsigned short* probe = (const unsigned short*)A_log;

  char* p = (char*)d_ws;
  auto alloc = [&](size_t bytes) { char* r = p; p += (bytes + 255) & ~255ull; return r; };
  bf16*  x_bf   = (bf16*) alloc((size_t)T_TOK * D_MODEL * 2);          // 8.4 MB
  bf16*  inw_bf = (bf16*) alloc((size_t)2 * D_INNER * D_MODEL * 2);    // 8.4 MB
  bf16*  xpw_bf = (bf16*) alloc((size_t)NXP * D_INNER * 2);            // 0.4 MB
  bf16*  dtw_bf = (bf16*) alloc((size_t)D_INNER * DT_RANK * 2);        // 0.26 MB
  bf16*  outw_bf= (bf16*) alloc((size_t)D_MODEL * D_INNER * 2);        // 4.2 MB
  float* params = (float*)alloc((size_t)P_TOT * 4);                    // 0.2 MB
  bf16*  scratch= (bf16*) alloc((size_t)T_TOK * D_INNER * 2);          // 16.8 MB (xparts, then y_bf)
  bf16*  z_silu = (bf16*) alloc((size_t)T_TOK * D_INNER * 2);          // 16.8 MB (then outproj partials)
  bf16*  uc_bf  = (bf16*) alloc((size_t)T_TOK * D_INNER * 2);          // 16.8 MB
  float* Bbuf   = (float*)alloc((size_t)T_TOK * D_STATE * 4);          // 0.26 MB
  float* Cbuf   = (float*)alloc((size_t)T_TOK * D_STATE * 4);          // 0.26 MB
  bf16*  dtb    = (bf16*) alloc((size_t)T_TOK * D_INNER * 2);          // 16.8 MB
  float* hend   = (float*)alloc((size_t)B_SZ * NC * D_INNER * 16 * 4); // 8.4 MB
  float* sumdt  = (float*)alloc((size_t)B_SZ * NC * D_INNER * 4);      // 0.5 MB
  float* xparts = (float*)scratch;  // 12.6 MB <= 16.8 MB
  bf16*  y_bf   = scratch;          // xparts dead after dtfuse
  bf16*  oparts = z_silu;           // z dead after pass3; bf16[2][4096][1024]

  dim3 blk(256);
  dim3 blk512(512);
  // 0) normalize ALL inputs in one launch (dtype-agnostic, vectorized)
  cvt_all<<<5304, blk, 0, stream>>>(x, in_w, xproj_w, dtproj_w, out_w,
                                    conv_w, conv_b, dtproj_b, A_log, Dw, ln_w, ln_b,
                                    x_bf, inw_bf, xpw_bf, dtw_bf, outw_bf, params, probe);

  // 1) in_proj + FUSED conv+silu (u_pre never hits HBM; conv kernel gone)
  k_inproj<<<dim3(T_TOK / 256, (2 * D_INNER) / 128), blk512, 0, stream>>>(
      x_bf, inw_bf, uc_bf, z_silu, params + P_CONVW, params + P_CONVB);
  // 2) x_proj split-K (register staging) -> f32 partials
  k_xproj<<<dim3(T_TOK / 128, 1, KSPLIT), blk, 0, stream>>>(uc_bf, xpw_bf, xparts);
  // 3) FUSED partial-reduce + dt_proj + softplus -> Bbuf/Cbuf/dtb
  k_dtfuse<<<dim3(16, 32), blk, 0, stream>>>(xparts, dtw_bf, params + P_DTB, Bbuf, Cbuf, dtb);
  // 4-6) chunked selective scan (pass2 parallel prefix)
  scan_pass1<<<B_SZ * NC * (D_INNER / 256), blk, 0, stream>>>(dtb, uc_bf, Bbuf, params + P_ALOG, hend, sumdt);
  scan_pass2<<<(B_SZ * D_INNER) / 2, blk, 0, stream>>>(hend, sumdt, params + P_ALOG);
  scan_pass3<<<B_SZ * NC * (D_INNER / 256), blk, 0, stream>>>(
      dtb, uc_bf, Bbuf, Cbuf, z_silu, hend, params + P_ALOG, params + P_DW, y_bf);
  // 7) out_proj split-K=2 (R2 pipelined body) -> oparts bf16 [2][t][1024]
  k_outproj<<<dim3(T_TOK / 256, D_MODEL / 128, 2), blk512, 0, stream>>>(y_bf, outw_bf, oparts);
  // 8) layernorm (fused 2-way bf16 split-K reduce + residual) -> d_out
  ln_kernel<<<T_TOK, blk, 0, stream>>>(oparts, x_bf, params + P_LNW, params + P_LNB, d_out, probe);
}

// Round 8
// 266.541 us; speedup vs baseline: 1.5352x; 1.1053x over previous
//
#include <hip/hip_runtime.h>
#include <hip/hip_bf16.h>
#include <math.h>

#define DEV static __device__ __forceinline__

typedef __hip_bfloat16 bf16;
typedef __attribute__((ext_vector_type(8))) short bf16x8;   // 8 bf16 = 4 VGPRs
typedef __attribute__((ext_vector_type(4))) short bf16x4;   // 4 bf16 = 2 VGPRs
typedef __attribute__((ext_vector_type(4))) float f32x4;

static constexpr int D_MODEL = 1024;
static constexpr int D_INNER = 2048;
static constexpr int D_STATE = 16;
static constexpr int DT_RANK = 64;
static constexpr int B_SZ   = 2;
static constexpr int L_SEQ  = 2048;
static constexpr int T_TOK  = B_SZ * L_SEQ;   // 4096 tokens
static constexpr int LC     = 64;             // scan chunk length
static constexpr int NC     = L_SEQ / LC;     // 32 chunks per sequence
static constexpr int NXP    = DT_RANK + 2 * D_STATE;   // 96
static constexpr int KSPLIT = 8;              // x_proj split-K factor

// params (f32) layout inside ws
static constexpr int P_CONVW = 0;        // [2048*4]
static constexpr int P_CONVB = 8192;     // [2048]
static constexpr int P_DTB   = 10240;    // [2048]
static constexpr int P_ALOG  = 12288;    // [2048*16]
static constexpr int P_DW    = 45056;    // [2048]
static constexpr int P_LNW   = 47104;    // [1024]
static constexpr int P_LNB   = 48128;    // [1024]
static constexpr int P_TOT   = 49152;

DEV float bf2f(bf16 x) { return __bfloat162float(x); }
DEV bf16  f2bf(float x) { return __float2bfloat16(x); }
DEV float sigmoidf_(float x) { return 1.0f / (1.0f + __expf(-x)); }
DEV float s2f(short s) { bf16 b; __builtin_memcpy(&b, &s, 2); return bf2f(b); }
DEV short f2s(float x) { bf16 b = f2bf(x); short s; __builtin_memcpy(&s, &b, 2); return s; }

DEV bool probe_f32(const unsigned short* probe) { return probe[1] == 0; }

DEV void async_copy16(const void* g, void* l) {
  // DMA 16 B/lane: LDS dest = wave-uniform base + lane*16 (m97-verified)
  __builtin_amdgcn_global_load_lds(
      (const __attribute__((address_space(1))) void*)g,
      (__attribute__((address_space(3))) void*)l, 16, 0, 0);
}

template <int N>
DEV void vm_wait() {
  if constexpr (N == 6) asm volatile("s_waitcnt vmcnt(6)" ::: "memory");
  else                  asm volatile("s_waitcnt vmcnt(0)" ::: "memory");
}

// ---------------------------------------------------------------------------
// fused input normalization: ALL 12 tensors in one launch (8 elems/thread)
// ---------------------------------------------------------------------------
__global__ void cvt_all(const void* s0, const void* s1, const void* s2,
                        const void* s3, const void* s4,
                        const void* s5, const void* s6, const void* s7,
                        const void* s8, const void* s9, const void* s10,
                        const void* s11,
                        bf16* d0, bf16* d1, bf16* d2, bf16* d3, bf16* d4,
                        float* params,
                        const unsigned short* __restrict__ probe)
{
  long i = (long)(blockIdx.x * 256 + threadIdx.x) * 8;
  const void* src; long off;
  bf16* dstb = nullptr; float* dstf = nullptr;
  if      (i <  4194304) { src = s0;  dstb = d0; off = i; }
  else if (i <  8388608) { src = s1;  dstb = d1; off = i - 4194304; }
  else if (i <  8585216) { src = s2;  dstb = d2; off = i - 8388608; }
  else if (i <  8716288) { src = s3;  dstb = d3; off = i - 8585216; }
  else if (i < 10813440) { src = s4;  dstb = d4; off = i - 8716288; }
  else if (i < 10821632) { src = s5;  dstf = params + P_CONVW; off = i - 10813440; }
  else if (i < 10823680) { src = s6;  dstf = params + P_CONVB; off = i - 10821632; }
  else if (i < 10825728) { src = s7;  dstf = params + P_DTB;   off = i - 10823680; }
  else if (i < 10858496) { src = s8;  dstf = params + P_ALOG;  off = i - 10825728; }
  else if (i < 10860544) { src = s9;  dstf = params + P_DW;    off = i - 10858496; }
  else if (i < 10861568) { src = s10; dstf = params + P_LNW;   off = i - 10860544; }
  else if (i < 10862592) { src = s11; dstf = params + P_LNB;   off = i - 10861568; }
  else return;
  bool isf32 = probe_f32(probe);
  float v[8];
  if (isf32) {
    float4 a = *(const float4*)((const float*)src + off);
    float4 b = *(const float4*)((const float*)src + off + 4);
    v[0]=a.x; v[1]=a.y; v[2]=a.z; v[3]=a.w;
    v[4]=b.x; v[5]=b.y; v[6]=b.z; v[7]=b.w;
  } else {
    bf16x8 t = *(const bf16x8*)((const bf16*)src + off);
    #pragma unroll
    for (int k = 0; k < 8; ++k) { short sk = t[k]; v[k] = s2f(sk); }
  }
  if (dstb) {
    bf16x8 o;
    #pragma unroll
    for (int k = 0; k < 8; ++k) o[k] = f2s(v[k]);
    *(bf16x8*)(dstb + off) = o;
  } else {
    f32x4 a = {v[0], v[1], v[2], v[3]};
    f32x4 b = {v[4], v[5], v[6], v[7]};
    *(f32x4*)(dstf + off)     = a;
    *(f32x4*)(dstf + off + 4) = b;
  }
}

// ---------------------------------------------------------------------------
// 8-wave counted-vmcnt pipelined GEMM (R2 config): BM=256, BN=128, BK=64,
// waves own 64x64 sub-tiles. LDS 3-slot ring (144 KiB), prefetch distance 2,
// vmcnt(6) per tile. 128B LDS rows + 8-chunk XOR swizzle.
// MODE 0: in_proj + FUSED conv+silu epilogue via HALO EXCHANGE:
//   u-half: acc -> LDS u-tile; store first-3/last-3 u rows to halo bufs;
//   conv rows 3..255 in-tile (0..2 at seq starts); boundary rows deferred
//   to k_convfix. z-half: silu -> z_silu. u_pre NEVER hits HBM in bulk.
// MODE 3: out_proj split-K=2 -> o0 = bf16 partials [kz][t][1024]
// ---------------------------------------------------------------------------
static constexpr int SLOT = 48 * 1024;
static constexpr int BOFF = 32 * 1024;

DEV void stage_A(const bf16* __restrict__ A, int ld, int bm, int k0,
                 char* slot, int tid) {
  #pragma unroll
  for (int j = 0; j < 4; ++j) {
    int p   = j * 8192 + tid * 16;           // linear LDS dest byte
    int row = p >> 7;                        // 0..255 (128B rows)
    int ck  = ((p >> 4) & 7) ^ (row & 7);    // inverse-swizzled 16B chunk
    async_copy16(A + (size_t)(bm + row) * ld + k0 + ck * 8,
                 slot + j * 8192 + (tid >> 6) * 1024);
  }
}

DEV void stage_B(const bf16* __restrict__ B, int ld, int bn, int k0,
                 char* slot, int tid) {
  #pragma unroll
  for (int j = 0; j < 2; ++j) {
    int p   = j * 8192 + tid * 16;
    int row = p >> 7;                        // 0..127
    int ck  = ((p >> 4) & 7) ^ (row & 7);
    async_copy16(B + (size_t)(bn + row) * ld + k0 + ck * 8,
                 slot + BOFF + j * 8192 + (tid >> 6) * 1024);
  }
}

template <int MODE>
DEV void gemm_pipe(const bf16* __restrict__ A, const bf16* __restrict__ B,
                   int M, int K, int ld,
                   void* __restrict__ o0, void* __restrict__ o1,
                   const float* __restrict__ cw, const float* __restrict__ cb,
                   bf16* __restrict__ ufirst, bf16* __restrict__ ulast)
{
  __shared__ __align__(16) char ring[3 * SLOT];   // 144 KiB
  if (MODE == 3) {
    A += (size_t)blockIdx.z * K;
    B += (size_t)blockIdx.z * K;
  }
  const int tid  = threadIdx.x;
  const int wave = tid >> 6;
  const int lane = tid & 63;
  const int bm = blockIdx.x * 256;
  const int bn = blockIdx.y * 128;
  const int wm = (wave >> 1) * 64;       // 0..192: A row group
  const int wn = (wave & 1) * 64;        // 0/64:   B row group
  const int fr = lane & 15;
  const int fq = lane >> 4;              // 0..3
  const int NT = K / 64;

  f32x4 acc[4][4];
  #pragma unroll
  for (int i = 0; i < 4; ++i)
    #pragma unroll
    for (int j = 0; j < 4; ++j)
      #pragma unroll
      for (int r = 0; r < 4; ++r) acc[i][j][r] = 0.0f;

  // prologue: stage tiles 0 and 1 (12 loads/thread in flight)
  stage_A(A, ld, bm, 0,  ring,        tid);
  stage_B(B, ld, bn, 0,  ring,        tid);
  stage_A(A, ld, bm, 64, ring + SLOT, tid);
  stage_B(B, ld, bn, 64, ring + SLOT, tid);

  int scur = 0;
  #pragma unroll 1
  for (int tk = 0; tk < NT; ++tk) {
    if (tk < NT - 1) vm_wait<6>();
    else             vm_wait<0>();
    __builtin_amdgcn_sched_barrier(0);
    __builtin_amdgcn_s_barrier();
    __builtin_amdgcn_sched_barrier(0);

    const char* sa = ring + scur * SLOT;
    int snxt = scur + 2; if (snxt >= 3) snxt -= 3;
    char* sn = ring + snxt * SLOT;

    // ---- phase 0: A frags (8 reads) + B frags ni=0..1 (4 reads) ----
    bf16x8 af[4][2], bg[2][2];
    #pragma unroll
    for (int mi = 0; mi < 4; ++mi)
      #pragma unroll
      for (int kk = 0; kk < 2; ++kk) {
        int row = wm + mi * 16 + fr;
        af[mi][kk] = *(const bf16x8*)(sa + row * 128 + (((kk * 4 + fq) ^ (fr & 7)) * 16));
      }
    #pragma unroll
    for (int ni = 0; ni < 2; ++ni)
      #pragma unroll
      for (int kk = 0; kk < 2; ++kk) {
        int row = wn + ni * 16 + fr;
        bg[ni][kk] = *(const bf16x8*)(sa + BOFF + row * 128 + (((kk * 4 + fq) ^ (fr & 7)) * 16));
      }
    __builtin_amdgcn_sched_barrier(0);
    if (tk + 2 < NT) stage_A(A, ld, bm, (tk + 2) * 64, sn, tid);
    __builtin_amdgcn_sched_barrier(0);
    asm volatile("s_waitcnt lgkmcnt(0)" ::: "memory");
    __builtin_amdgcn_sched_barrier(0);
    __builtin_amdgcn_s_setprio(1);
    #pragma unroll
    for (int kk = 0; kk < 2; ++kk)
      #pragma unroll
      for (int mi = 0; mi < 4; ++mi)
        #pragma unroll
        for (int ni = 0; ni < 2; ++ni)
          acc[mi][ni] = __builtin_amdgcn_mfma_f32_16x16x32_bf16(af[mi][kk], bg[ni][kk], acc[mi][ni], 0, 0, 0);
    __builtin_amdgcn_s_setprio(0);
    __builtin_amdgcn_sched_barrier(0);

    // ---- phase 1: B frags ni=2..3 (4 reads), A frags reused ----
    bf16x8 bh[2][2];
    #pragma unroll
    for (int ni = 0; ni < 2; ++ni)
      #pragma unroll
      for (int kk = 0; kk < 2; ++kk) {
        int row = wn + (ni + 2) * 16 + fr;
        bh[ni][kk] = *(const bf16x8*)(sa + BOFF + row * 128 + (((kk * 4 + fq) ^ (fr & 7)) * 16));
      }
    __builtin_amdgcn_sched_barrier(0);
    if (tk + 2 < NT) stage_B(B, ld, bn, (tk + 2) * 64, sn, tid);
    __builtin_amdgcn_sched_barrier(0);
    asm volatile("s_waitcnt lgkmcnt(0)" ::: "memory");
    __builtin_amdgcn_sched_barrier(0);
    __builtin_amdgcn_s_setprio(1);
    #pragma unroll
    for (int kk = 0; kk < 2; ++kk)
      #pragma unroll
      for (int mi = 0; mi < 4; ++mi)
        #pragma unroll
        for (int ni = 0; ni < 2; ++ni)
          acc[mi][ni + 2] = __builtin_amdgcn_mfma_f32_16x16x32_bf16(af[mi][kk], bh[ni][kk], acc[mi][ni + 2], 0, 0, 0);
    __builtin_amdgcn_s_setprio(0);
    __builtin_amdgcn_sched_barrier(0);

    scur = (scur + 1 == 3) ? 0 : scur + 1;
  }

  const int er = (lane >> 4) * 4;     // C/D: row = er + reg, col = lane&15
  const int ec = lane & 15;

  if (MODE == 3) {
    #pragma unroll
    for (int mi = 0; mi < 4; ++mi)
      #pragma unroll
      for (int ni = 0; ni < 4; ++ni)
        #pragma unroll
        for (int r = 0; r < 4; ++r) {
          int row = bm + wm + mi * 16 + er + r;
          int col = bn + wn + ni * 16 + ec;
          ((bf16*)o0)[((size_t)blockIdx.z * M + row) * D_MODEL + col] = f2bf(acc[mi][ni][r]);
        }
    return;
  }

  // ================= MODE 0 fused epilogue =================
  if (bn >= D_INNER) {
    // z-half: silu -> z_silu
    #pragma unroll
    for (int mi = 0; mi < 4; ++mi)
      #pragma unroll
      for (int ni = 0; ni < 4; ++ni)
        #pragma unroll
        for (int r = 0; r < 4; ++r) {
          int row = bm + wm + mi * 16 + er + r;
          int col = bn + wn + ni * 16 + ec - D_INNER;
          float v = acc[mi][ni][r];
          ((bf16*)o1)[(size_t)row * D_INNER + col] = f2bf(v * sigmoidf_(v));
        }
    return;
  }

  // u-half: fused causal conv (W=4) + bias + silu via halo exchange.
  // LDS (reusing ring): u tile [256][136] bf16 (136-stride breaks the
  // 256B-row bank alias), then cws[128][4] f32, cbs[128] f32.
  __syncthreads();                        // all ring reads done
  bf16*  uT  = (bf16*)ring;               // 256*136*2 = 69632 B
  float* cws = (float*)(ring + 70656);
  float* cbs = (float*)(ring + 72704);

  #pragma unroll
  for (int mi = 0; mi < 4; ++mi)
    #pragma unroll
    for (int ni = 0; ni < 4; ++ni)
      #pragma unroll
      for (int r = 0; r < 4; ++r)
        uT[(size_t)(wm + mi * 16 + er + r) * 136 + wn + ni * 16 + ec] = f2bf(acc[mi][ni][r]);

  if (tid < 128) {
    *(f32x4*)(cws + tid * 4) = *(const f32x4*)(cw + (size_t)(bn + tid) * 4);
    cbs[tid] = cb[bn + tid];
  }
  __syncthreads();

  // halo exchange: store first-3 and last-3 u_pre rows (this col strip)
  if (tid < 48) {
    int i  = tid >> 4;                    // 0..2
    int c8 = (tid & 15) * 8;
    size_t hb = ((size_t)(bm >> 8) * 3 + i) * D_INNER + bn + c8;
    *(bf16x8*)(ufirst + hb) = *(const bf16x8*)(uT + (size_t)i * 136 + c8);
    *(bf16x8*)(ulast  + hb) = *(const bf16x8*)(uT + (size_t)(253 + i) * 136 + c8);
  }

  // conv + silu -> uc. Thread t: col-group cg = t&15 (8 cols), rows
  // (t>>4) + j*32. Rows 0..2 deferred to k_convfix unless seq start.
  const int cg = tid & 15;
  float cwr[4][8], cbr[8];
  #pragma unroll
  for (int i = 0; i < 8; ++i) {
    f32x4 w4 = *(const f32x4*)(cws + (cg * 8 + i) * 4);
    cwr[0][i] = w4[0]; cwr[1][i] = w4[1]; cwr[2][i] = w4[2]; cwr[3][i] = w4[3];
    cbr[i] = cbs[cg * 8 + i];
  }
  const int lbase = bm & (L_SEQ - 1);
  #pragma unroll
  for (int j = 0; j < 8; ++j) {
    int row = (tid >> 4) + j * 32;        // 0..255
    if (row < 3 && lbase != 0) continue;  // boundary token -> k_convfix
    float a8[8];
    #pragma unroll
    for (int i = 0; i < 8; ++i) a8[i] = cbr[i];
    #pragma unroll
    for (int w = 0; w < 4; ++w) {
      if (row - 3 + w >= 0) {             // in-tile tap (causal zero-pad)
        bf16x8 u8 = *(const bf16x8*)(uT + (size_t)(row - 3 + w) * 136 + cg * 8);
        #pragma unroll
        for (int i = 0; i < 8; ++i) { short uu = u8[i]; a8[i] += s2f(uu) * cwr[w][i]; }
      }
    }
    bf16x8 o;
    #pragma unroll
    for (int i = 0; i < 8; ++i) o[i] = f2s(a8[i] * sigmoidf_(a8[i]));
    *(bf16x8*)((bf16*)o0 + (size_t)(bm + row) * D_INNER + bn + cg * 8) = o;
  }
}

// ---------------------------------------------------------------------------
// conv fixup: finish the 3 boundary tokens of each non-seq-start row-block
// (14 boundaries x 3 tokens x 2048 cols) from the exchanged halos.
// ---------------------------------------------------------------------------
__global__ void __launch_bounds__(256) k_convfix(
    const bf16* __restrict__ ufirst, const bf16* __restrict__ ulast,
    const float* __restrict__ cw, const float* __restrict__ cb,
    bf16* __restrict__ uc_bf)
{
  int idx = blockIdx.x * 256 + threadIdx.x;   // over 42*2048/4 = 21504
  int e4 = idx * 4;
  int ti = e4 >> 11;            // 0..41
  int c4 = e4 & 2047;
  int tb = ti / 3, r = ti - tb * 3;
  int rb = (tb < 7) ? tb + 1 : tb + 2;        // skip seq starts (rb 0, 8)
  int token = rb * 256 + r;
  float a[4];
  float4 wv[4];
  #pragma unroll
  for (int i = 0; i < 4; ++i) {
    a[i]  = cb[c4 + i];
    wv[i] = *(const float4*)(cw + (size_t)(c4 + i) * 4);
  }
  #pragma unroll
  for (int w = 0; w < 4; ++w) {
    int g = r - 3 + w;
    const bf16* srcrow = (g < 0)
        ? (ulast  + ((size_t)(rb - 1) * 3 + (g + 3)) * D_INNER)
        : (ufirst + ((size_t)rb * 3 + g) * D_INNER);
    bf16x4 u = *(const bf16x4*)(srcrow + c4);
    #pragma unroll
    for (int i = 0; i < 4; ++i) { short su = u[i]; a[i] += s2f(su) * ((const float*)&wv[i])[w]; }
  }
  bf16x4 o;
  #pragma unroll
  for (int i = 0; i < 4; ++i) o[i] = f2s(a[i] * sigmoidf_(a[i]));
  *(bf16x4*)(uc_bf + (size_t)token * D_INNER + c4) = o;
}

// ---------------------------------------------------------------------------
// BK=32 register-staged GEMM body (x_proj split-K -> f32 partials)
// ---------------------------------------------------------------------------
__global__ void __launch_bounds__(256) k_xproj(const bf16* __restrict__ A,
                                               const bf16* __restrict__ B,
                                               float* __restrict__ o0)
{
  __shared__ __align__(16) bf16 As[128 * 32];
  __shared__ __align__(16) bf16 Bs[128 * 32];
  const int M = T_TOK, N = NXP, K = D_INNER / KSPLIT, ld = D_INNER;
  A += (size_t)blockIdx.z * K;
  B += (size_t)blockIdx.z * K;
  const int tid  = threadIdx.x;
  const int wave = tid >> 6;
  const int lane = tid & 63;
  const int bm = blockIdx.x * 128;
  const int bn = 0;
  const int wm = (wave >> 1) * 64;
  const int wn = (wave & 1) * 64;

  f32x4 acc[4][4];
  #pragma unroll
  for (int i = 0; i < 4; ++i)
    #pragma unroll
    for (int j = 0; j < 4; ++j)
      #pragma unroll
      for (int r = 0; r < 4; ++r) acc[i][j][r] = 0.0f;

  const int ar0 = tid >> 2;
  const int ar1 = ar0 + 64;
  const int ac  = (tid & 3) * 8;
  const int fr = lane & 15;
  const int fk = (lane >> 4) * 8;

  for (int k0 = 0; k0 < K; k0 += 32) {
    bf16x8 a0 = *(const bf16x8*)(A + (size_t)(bm + ar0) * ld + k0 + ac);
    bf16x8 a1 = *(const bf16x8*)(A + (size_t)(bm + ar1) * ld + k0 + ac);
    int r0 = bn + ar0; if (r0 > N - 1) r0 = N - 1;
    int r1 = bn + ar1; if (r1 > N - 1) r1 = N - 1;
    bf16x8 b0 = *(const bf16x8*)(B + (size_t)r0 * ld + k0 + ac);
    bf16x8 b1 = *(const bf16x8*)(B + (size_t)r1 * ld + k0 + ac);
    __syncthreads();
    *(bf16x8*)(As + ar0 * 32 + ac) = a0;
    *(bf16x8*)(As + ar1 * 32 + ac) = a1;
    *(bf16x8*)(Bs + ar0 * 32 + ac) = b0;
    *(bf16x8*)(Bs + ar1 * 32 + ac) = b1;
    __syncthreads();

    bf16x8 af[4], bg[4];
    #pragma unroll
    for (int mi = 0; mi < 4; ++mi)
      af[mi] = *(const bf16x8*)(As + (wm + mi * 16 + fr) * 32 + fk);
    #pragma unroll
    for (int ni = 0; ni < 4; ++ni)
      bg[ni] = *(const bf16x8*)(Bs + (wn + ni * 16 + fr) * 32 + fk);
    #pragma unroll
    for (int mi = 0; mi < 4; ++mi)
      #pragma unroll
      for (int ni = 0; ni < 4; ++ni)
        acc[mi][ni] = __builtin_amdgcn_mfma_f32_16x16x32_bf16(af[mi], bg[ni], acc[mi][ni], 0, 0, 0);
  }

  const int er = (lane >> 4) * 4;
  const int ec = lane & 15;
  #pragma unroll
  for (int mi = 0; mi < 4; ++mi)
    #pragma unroll
    for (int ni = 0; ni < 4; ++ni)
      #pragma unroll
      for (int r = 0; r < 4; ++r) {
        int row = bm + wm + mi * 16 + er + r;
        int col = bn + wn + ni * 16 + ec;
        if (col >= N) continue;
        o0[((size_t)blockIdx.z * M + row) * N + col] = acc[mi][ni][r];
      }
}

// distinct names so rocprof disambiguates the stages
__global__ void __launch_bounds__(512) k_inproj(const bf16* A, const bf16* B,
    void* o0, void* o1, const float* cw, const float* cb,
    bf16* ufirst, bf16* ulast) {
  gemm_pipe<0>(A, B, T_TOK, D_MODEL, D_MODEL, o0, o1, cw, cb, ufirst, ulast);
}
__global__ void __launch_bounds__(512) k_outproj(const bf16* A, const bf16* B,
    void* o0) {
  gemm_pipe<3>(A, B, T_TOK, D_INNER / 2, D_INNER, o0, nullptr, nullptr, nullptr,
               nullptr, nullptr);
}

// ---------------------------------------------------------------------------
// FUSED x_proj split-K reduce + dt_proj GEMM + softplus (512 blocks).
// ---------------------------------------------------------------------------
__global__ __launch_bounds__(256) void k_dtfuse(
    const float* __restrict__ partials,   // [8][T_TOK][96]
    const bf16*  __restrict__ dtw,        // [2048][64] bf16
    const float* __restrict__ dtbias,     // [2048] f32
    float* __restrict__ Bbuf, float* __restrict__ Cbuf,
    bf16* __restrict__ dtb)
{
  __shared__ __align__(16) bf16 Al[128 * 72];   // 18 KB (dtlr tile, pad 72)
  __shared__ __align__(16) bf16 Bl[128 * 72];   // 18 KB (dtw tile)
  const int tid = threadIdx.x;
  unsigned lin = blockIdx.x + gridDim.x * blockIdx.y;
  unsigned nid = (lin & 7) * 64 + (lin >> 3);   // nwg=512, cpx=64
  const int cblk = nid & 15;
  const int tblk = nid >> 4;
  const int r0 = tblk * 128;
  const int c0 = cblk * 128;

  #pragma unroll
  for (int it = 0; it < 8; ++it) {
    int idx = it * 256 + tid;            // 128 rows x 16 f32x4 groups
    int row = idx >> 4;
    int g   = idx & 15;
    f32x4 s = {0.0f, 0.0f, 0.0f, 0.0f};
    #pragma unroll
    for (int kz = 0; kz < KSPLIT; ++kz)
      s += *(const f32x4*)(partials + ((size_t)kz * T_TOK + r0 + row) * NXP + g * 4);
    bf16x4 o;
    #pragma unroll
    for (int k = 0; k < 4; ++k) o[k] = f2s(s[k]);
    *(bf16x4*)(Al + row * 72 + g * 4) = o;
  }
  if (cblk == 0) {
    #pragma unroll
    for (int it = 0; it < 4; ++it) {
      int idx = it * 256 + tid;          // 128 rows x 8 groups
      int row = idx >> 3;
      int g   = 16 + (idx & 7);
      f32x4 s = {0.0f, 0.0f, 0.0f, 0.0f};
      #pragma unroll
      for (int kz = 0; kz < KSPLIT; ++kz)
        s += *(const f32x4*)(partials + ((size_t)kz * T_TOK + r0 + row) * NXP + g * 4);
      if (g < 20) *(f32x4*)(Bbuf + (size_t)(r0 + row) * D_STATE + (g - 16) * 4) = s;
      else        *(f32x4*)(Cbuf + (size_t)(r0 + row) * D_STATE + (g - 20) * 4) = s;
    }
  }
  #pragma unroll
  for (int it = 0; it < 4; ++it) {
    int idx = it * 256 + tid;            // 1024 bf16x8 groups
    int row = idx >> 3;
    int cv  = (idx & 7) * 8;
    *(bf16x8*)(Bl + row * 72 + cv) = *(const bf16x8*)(dtw + (size_t)(c0 + row) * 64 + cv);
  }
  __syncthreads();

  const int wave = tid >> 6;
  const int lane = tid & 63;
  const int wm = (wave >> 1) * 64;
  const int wn = (wave & 1) * 64;
  const int fr = lane & 15;
  const int fk = (lane >> 4) * 8;
  const int er = (lane >> 4) * 4;
  const int ec = lane & 15;

  f32x4 acc[4][4];
  #pragma unroll
  for (int i = 0; i < 4; ++i)
    #pragma unroll
    for (int j = 0; j < 4; ++j)
      #pragma unroll
      for (int r = 0; r < 4; ++r) acc[i][j][r] = 0.0f;

  #pragma unroll
  for (int k0 = 0; k0 < 64; k0 += 32) {
    bf16x8 af[4], bg[4];
    #pragma unroll
    for (int mi = 0; mi < 4; ++mi)
      af[mi] = *(const bf16x8*)(Al + (wm + mi * 16 + fr) * 72 + k0 + fk);
    #pragma unroll
    for (int ni = 0; ni < 4; ++ni)
      bg[ni] = *(const bf16x8*)(Bl + (wn + ni * 16 + fr) * 72 + k0 + fk);
    #pragma unroll
    for (int mi = 0; mi < 4; ++mi)
      #pragma unroll
      for (int ni = 0; ni < 4; ++ni)
        acc[mi][ni] = __builtin_amdgcn_mfma_f32_16x16x32_bf16(af[mi], bg[ni], acc[mi][ni], 0, 0, 0);
  }

  #pragma unroll
  for (int mi = 0; mi < 4; ++mi)
    #pragma unroll
    for (int ni = 0; ni < 4; ++ni)
      #pragma unroll
      for (int r = 0; r < 4; ++r) {
        int orow = r0 + wm + mi * 16 + er + r;
        int ocol = c0 + wn + ni * 16 + ec;
        float v = acc[mi][ni][r] + dtbias[ocol];
        float sp = (v > 15.0f) ? v : __logf(1.0f + __expf(v));
        dtb[(size_t)orow * D_INNER + ocol] = f2bf(sp);
      }
}

// ---------------------------------------------------------------------------
// helpers for the scan kernels
// ---------------------------------------------------------------------------
DEV void load_Ad(const float* A_log, int d, float* Ad, bool& fast) {
  fast = true;
  #pragma unroll
  for (int n = 0; n < 16; ++n) {
    Ad[n] = -__expf(A_log[d * 16 + n]);
    fast = fast && (fabsf(Ad[n] + (float)(n + 1)) < 1e-3f * (n + 1));
  }
}
DEV void compute_decay(bool fast, float dtv, const float* Ad, float* dec) {
  if (fast) {                       // A_n = -(n+1): decay_n = exp(-dt)^(n+1)
    float e1 = __expf(-dtv);
    float en = e1;
    #pragma unroll
    for (int n = 0; n < 16; ++n) { dec[n] = en; en *= e1; }
  } else {
    #pragma unroll
    for (int n = 0; n < 16; ++n) dec[n] = __expf(Ad[n] * dtv);
  }
}

// ---------------------------------------------------------------------------
// Scan pass 1: per-(b,chunk,d) local scan from h=0 -> chunk-end state + sum(dt)
// ---------------------------------------------------------------------------
__global__ __launch_bounds__(256) void scan_pass1(
    const bf16* __restrict__ dt, const bf16* __restrict__ uc_bf,
    const float* __restrict__ Bbuf, const float* __restrict__ A_log,
    float* __restrict__ hend, float* __restrict__ sumdt)
{
  __shared__ float Bs4[LC * D_STATE];         // 4 KB
  __shared__ bf16 dts[16 * 256];              // 8 KB
  __shared__ bf16 uts[16 * 256];              // 8 KB
  int bid = blockIdx.x;
  int tid = threadIdx.x;
  int dt8 = bid & 7;
  int c = (bid >> 3) & (NC - 1);
  int b = bid >> 8;
  int d0 = dt8 * 256;
  int d  = d0 + tid;
  int t0g = b * L_SEQ + c * LC;

  ((f32x4*)Bs4)[tid] = ((const f32x4*)(Bbuf + (size_t)t0g * D_STATE))[tid];

  float Ad[16], h[16];
  bool fast;
  load_Ad(A_log, d, Ad, fast);
  #pragma unroll
  for (int n = 0; n < 16; ++n) h[n] = 0.0f;
  float sdt = 0.0f;

  for (int sub = 0; sub < 4; ++sub) {
    __syncthreads();
    #pragma unroll
    for (int rep = 0; rep < 2; ++rep) {
      int idx = rep * 256 + tid;
      int row = idx >> 5;
      int col = (idx & 31) * 8;
      size_t src = (size_t)(t0g + sub * 16 + row) * D_INNER + d0 + col;
      *(bf16x8*)(dts + row * 256 + col) = *(const bf16x8*)(dt + src);
      *(bf16x8*)(uts + row * 256 + col) = *(const bf16x8*)(uc_bf + src);
    }
    __syncthreads();
    for (int t = 0; t < 16; ++t) {
      float dtv = bf2f(dts[t * 256 + tid]);
      float uv  = bf2f(uts[t * 256 + tid]);
      float su  = dtv * uv;
      sdt += dtv;
      float dec[16];
      compute_decay(fast, dtv, Ad, dec);
      const float* Bp = Bs4 + (sub * 16 + t) * 16;
      #pragma unroll
      for (int n = 0; n < 16; ++n)
        h[n] = h[n] * dec[n] + su * Bp[n];
    }
  }
  size_t base = ((size_t)(b * NC + c) * D_INNER + d) * 16;
  #pragma unroll
  for (int q = 0; q < 4; ++q)
    *(f32x4*)(hend + base + q * 4) = *(f32x4*)(h + q * 4);
  sumdt[(size_t)(b * NC + c) * D_INNER + d] = sdt;
}

// ---------------------------------------------------------------------------
// Scan pass 2: PARALLEL affine prefix scan over chunks.
// ---------------------------------------------------------------------------
__global__ __launch_bounds__(256) void scan_pass2(
    float* __restrict__ hend, const float* __restrict__ sumdt,
    const float* __restrict__ A_log)
{
  __shared__ float Ms[4][64];
  __shared__ float Es[4][64];
  int bid = blockIdx.x;                // 1024 blocks
  int tid = threadIdx.x;
  int cg   = tid >> 6;                 // 0..3
  int lane = tid & 63;
  int dloc = lane >> 4;                // 0..3
  int n    = lane & 15;
  int b     = bid >> 9;
  int d     = (bid & 511) * 4 + dloc;

  float a = -__expf(A_log[d * 16 + n]);

  float Ml[8], El[8];
  float M = 1.0f, E = 0.0f;
  #pragma unroll
  for (int j = 0; j < 8; ++j) {
    int c = cg * 8 + j;
    size_t sbase = (size_t)(b * NC + c) * D_INNER + d;
    float m = __expf(a * sumdt[sbase]);
    float e = hend[sbase * 16 + n];
    Ml[j] = M; El[j] = E;              // exclusive local prefix
    M = m * M;
    E = m * E + e;
  }
  Ms[cg][lane] = M;
  Es[cg][lane] = E;
  __syncthreads();
  float Ep = 0.0f;                     // exclusive group prefix (groups < cg)
  for (int g = 0; g < cg; ++g) {
    float Mg = Ms[g][lane], Eg = Es[g][lane];
    Ep = Mg * Ep + Eg;
  }
  #pragma unroll
  for (int j = 0; j < 8; ++j) {
    int c = cg * 8 + j;
    size_t sbase = (size_t)(b * NC + c) * D_INNER + d;
    hend[sbase * 16 + n] = Ml[j] * Ep + El[j];   // h at chunk start
  }
}

// ---------------------------------------------------------------------------
// Scan pass 3: re-scan with correct h0; y = (dot(h,C) + u*D) * silu(z) -> bf16
// ---------------------------------------------------------------------------
__global__ __launch_bounds__(256) void scan_pass3(
    const bf16* __restrict__ dt, const bf16* __restrict__ uc_bf,
    const float* __restrict__ Bbuf, const float* __restrict__ Cbuf,
    const bf16* __restrict__ z_silu, const float* __restrict__ hstart,
    const float* __restrict__ A_log, const float* __restrict__ Dw,
    bf16* __restrict__ y_bf)
{
  __shared__ float Bs4[LC * D_STATE];         // 4 KB
  __shared__ float Cs4[LC * D_STATE];         // 4 KB
  __shared__ bf16 dts[16 * 256];              // 8 KB
  __shared__ bf16 uts[16 * 256];              // 8 KB
  __shared__ bf16 zts[16 * 256];              // 8 KB
  int bid = blockIdx.x;
  int tid = threadIdx.x;
  int dt8 = bid & 7;
  int c = (bid >> 3) & (NC - 1);
  int b = bid >> 8;
  int d0 = dt8 * 256;
  int d  = d0 + tid;
  int t0g = b * L_SEQ + c * LC;

  ((f32x4*)Bs4)[tid] = ((const f32x4*)(Bbuf + (size_t)t0g * D_STATE))[tid];
  ((f32x4*)Cs4)[tid] = ((const f32x4*)(Cbuf + (size_t)t0g * D_STATE))[tid];

  float Ad[16], h[16];
  bool fast;
  load_Ad(A_log, d, Ad, fast);
  size_t base = ((size_t)(b * NC + c) * D_INNER + d) * 16;
  #pragma unroll
  for (int q = 0; q < 4; ++q)
    *(f32x4*)(h + q * 4) = *(const f32x4*)(hstart + base + q * 4);
  float Dv = Dw[d];

  for (int sub = 0; sub < 4; ++sub) {
    __syncthreads();
    #pragma unroll
    for (int rep = 0; rep < 2; ++rep) {
      int idx = rep * 256 + tid;
      int row = idx >> 5;
      int col = (idx & 31) * 8;
      size_t src = (size_t)(t0g + sub * 16 + row) * D_INNER + d0 + col;
      *(bf16x8*)(dts + row * 256 + col) = *(const bf16x8*)(dt + src);
      *(bf16x8*)(uts + row * 256 + col) = *(const bf16x8*)(uc_bf + src);
      *(bf16x8*)(zts + row * 256 + col) = *(const bf16x8*)(z_silu + src);
    }
    __syncthreads();
    for (int t = 0; t < 16; ++t) {
      float dtv = bf2f(dts[t * 256 + tid]);
      float uv  = bf2f(uts[t * 256 + tid]);
      float zv  = bf2f(zts[t * 256 + tid]);
      float su  = dtv * uv;
      float dec[16];
      compute_decay(fast, dtv, Ad, dec);
      const float* Bp = Bs4 + (sub * 16 + t) * 16;
      const float* Cp = Cs4 + (sub * 16 + t) * 16;
      float y = 0.0f;
      #pragma unroll
      for (int n = 0; n < 16; ++n) {
        h[n] = h[n] * dec[n] + su * Bp[n];
        y += h[n] * Cp[n];
      }
      y = (y + uv * Dv) * zv;
      y_bf[(size_t)(t0g + sub * 16 + t) * D_INNER + d] = f2bf(y);
    }
  }
}

// ---------------------------------------------------------------------------
// LayerNorm; fuses out_proj split-K=2 reduce (bf16 partials) + residual.
// ---------------------------------------------------------------------------
__global__ void ln_kernel(const bf16* __restrict__ parts,
                          const bf16* __restrict__ x_bf,
                          const float* __restrict__ w,
                          const float* __restrict__ bia,
                          void* __restrict__ out,
                          const unsigned short* __restrict__ probe)
{
  int t = blockIdx.x;
  int tid = threadIdx.x;
  const bf16* p0 = parts + (size_t)t * D_MODEL;
  const bf16* p1 = parts + ((size_t)T_TOK + t) * D_MODEL;
  const bf16* xr = x_bf + (size_t)t * D_MODEL;
  float v[4];
  float s = 0.0f, q = 0.0f;
  #pragma unroll
  for (int k = 0; k < 4; ++k) {
    int col = tid + k * 256;
    v[k] = bf2f(p0[col]) + bf2f(p1[col]) + bf2f(xr[col]);
    s += v[k]; q += v[k] * v[k];
  }
  #pragma unroll
  for (int off = 32; off >= 1; off >>= 1) {
    s += __shfl_down(s, off);
    q += __shfl_down(q, off);
  }
  __shared__ float red[8];
  __shared__ float mv[2];
  int wave = tid >> 6, lane = tid & 63;
  if (lane == 0) { red[wave] = s; red[4 + wave] = q; }
  __syncthreads();
  if (tid == 0) {
    float S = red[0] + red[1] + red[2] + red[3];
    float Q = red[4] + red[5] + red[6] + red[7];
    float mu = S * (1.0f / D_MODEL);
    float var = Q * (1.0f / D_MODEL) - mu * mu;
    mv[0] = mu; mv[1] = rsqrtf(var + 1e-5f);
  }
  __syncthreads();
  float mu = mv[0], rs = mv[1];
  bool isf32 = probe_f32(probe);
  #pragma unroll
  for (int k = 0; k < 4; ++k) {
    int col = tid + k * 256;
    float r = (v[k] - mu) * rs * w[col] + bia[col];
    if (isf32) ((float*)out)[(size_t)t * D_MODEL + col] = r;
    else       ((bf16*) out)[(size_t)t * D_MODEL + col] = f2bf(r);
  }
}

// ---------------------------------------------------------------------------
extern "C" void kernel_launch(void* const* d_in, const int* in_sizes, int n_in,
                              void* d_out, int out_size, void* d_ws, size_t ws_size,
                              hipStream_t stream)
{
  const void* x        = d_in[0];
  const void* in_w     = d_in[1];
  const void* conv_w   = d_in[2];
  const void* conv_b   = d_in[3];
  const void* xproj_w  = d_in[4];
  const void* dtproj_w = d_in[5];
  const void* dtproj_b = d_in[6];
  const void* A_log    = d_in[7];
  const void* Dw       = d_in[8];
  const void* out_w    = d_in[9];
  const void* ln_w     = d_in[10];
  const void* ln_b     = d_in[11];
  const unsigned short* probe = (const unsigned short*)A_log;

  char* p = (char*)d_ws;
  auto alloc = [&](size_t bytes) { char* r = p; p += (bytes + 255) & ~255ull; return r; };
  bf16*  x_bf   = (bf16*) alloc((size_t)T_TOK * D_MODEL * 2);          // 8.4 MB
  bf16*  inw_bf = (bf16*) alloc((size_t)2 * D_INNER * D_MODEL * 2);    // 8.4 MB
  bf16*  xpw_bf = (bf16*) alloc((size_t)NXP * D_INNER * 2);            // 0.4 MB
  bf16*  dtw_bf = (bf16*) alloc((size_t)D_INNER * DT_RANK * 2);        // 0.26 MB
  bf16*  outw_bf= (bf16*) alloc((size_t)D_MODEL * D_INNER * 2);        // 4.2 MB
  float* params = (float*)alloc((size_t)P_TOT * 4);                    // 0.2 MB
  bf16*  scratch= (bf16*) alloc((size_t)T_TOK * D_INNER * 2);          // 16.8 MB (xparts, then y_bf)
  bf16*  z_silu = (bf16*) alloc((size_t)T_TOK * D_INNER * 2);          // 16.8 MB (then outproj partials)
  bf16*  uc_bf  = (bf16*) alloc((size_t)T_TOK * D_INNER * 2);          // 16.8 MB
  float* Bbuf   = (float*)alloc((size_t)T_TOK * D_STATE * 4);          // 0.26 MB
  float* Cbuf   = (float*)alloc((size_t)T_TOK * D_STATE * 4);          // 0.26 MB
  bf16*  dtb    = (bf16*) alloc((size_t)T_TOK * D_INNER * 2);          // 16.8 MB
  float* hend   = (float*)alloc((size_t)B_SZ * NC * D_INNER * 16 * 4); // 8.4 MB
  float* sumdt  = (float*)alloc((size_t)B_SZ * NC * D_INNER * 4);      // 0.5 MB
  bf16*  ufirst = (bf16*) alloc((size_t)16 * 3 * D_INNER * 2);         // 0.2 MB
  bf16*  ulast  = (bf16*) alloc((size_t)16 * 3 * D_INNER * 2);         // 0.2 MB
  float* xparts = (float*)scratch;  // 12.6 MB <= 16.8 MB
  bf16*  y_bf   = scratch;          // xparts dead after dtfuse
  bf16*  oparts = z_silu;           // z dead after pass3; bf16[2][4096][1024]

  dim3 blk(256);
  dim3 blk512(512);
  // 0) normalize ALL inputs in one launch (dtype-agnostic, vectorized)
  cvt_all<<<5304, blk, 0, stream>>>(x, in_w, xproj_w, dtproj_w, out_w,
                                    conv_w, conv_b, dtproj_b, A_log, Dw, ln_w, ln_b,
                                    x_bf, inw_bf, xpw_bf, dtw_bf, outw_bf, params, probe);

  // 1) in_proj + FUSED conv+silu (halo exchange; u_pre never hits HBM in bulk)
  k_inproj<<<dim3(T_TOK / 256, (2 * D_INNER) / 128), blk512, 0, stream>>>(
      x_bf, inw_bf, uc_bf, z_silu, params + P_CONVW, params + P_CONVB, ufirst, ulast);
  // 1b) conv fixup: 42 boundary tokens from the exchanged halos
  k_convfix<<<84, blk, 0, stream>>>(ufirst, ulast, params + P_CONVW, params + P_CONVB, uc_bf);
  // 2) x_proj split-K (register staging) -> f32 partials
  k_xproj<<<dim3(T_TOK / 128, 1, KSPLIT), blk, 0, stream>>>(uc_bf, xpw_bf, xparts);
  // 3) FUSED partial-reduce + dt_proj + softplus -> Bbuf/Cbuf/dtb
  k_dtfuse<<<dim3(16, 32), blk, 0, stream>>>(xparts, dtw_bf, params + P_DTB, Bbuf, Cbuf, dtb);
  // 4-6) chunked selective scan (pass2 parallel prefix)
  scan_pass1<<<B_SZ * NC * (D_INNER / 256), blk, 0, stream>>>(dtb, uc_bf, Bbuf, params + P_ALOG, hend, sumdt);
  scan_pass2<<<(B_SZ * D_INNER) / 2, blk, 0, stream>>>(hend, sumdt, params + P_ALOG);
  scan_pass3<<<B_SZ * NC * (D_INNER / 256), blk, 0, stream>>>(
      dtb, uc_bf, Bbuf, Cbuf, z_silu, hend, params + P_ALOG, params + P_DW, y_bf);
  // 7) out_proj split-K=2 (R2 pipelined body) -> oparts bf16 [2][t][1024]
  k_outproj<<<dim3(T_TOK / 256, D_MODEL / 128, 2), blk512, 0, stream>>>(y_bf, outw_bf, oparts);
  // 8) layernorm (fused 2-way bf16 split-K reduce + residual) -> d_out
  ln_kernel<<<T_TOK, blk, 0, stream>>>(oparts, x_bf, params + P_LNW, params + P_LNB, d_out, probe);
}